// Round 9
// baseline (20413.135 us; speedup 1.0000x reference)
//
#include <hip/hip_runtime.h>
#include <math.h>

// ---------------- model constants ----------------
// HD=256 NL=4 NH=8 DH=32 MP=8 MS=32 T=40 ES=64 BATCH=8 BEAMS=5 BB=40
// START=1 END=2 MIN_LL_PEN=-100000
// Decode: 8 groups (batch) x 8 WGs x 512 thr. Column-sliced GEMMs, cross-WG
// data via relaxed agent-scope atomics (per-access coherent, NO L2 inv/wb),
// fence-free monotonic barrier. Wo/head/beam computed redundantly per WG.

// ---------------- conv kernels (proven rounds 3-6, unchanged) ----------------
template <int IC, int OC, int OD, int CHUNKS>
__global__ __launch_bounds__(256) void conv_v1(const float* __restrict__ in,
                                               const float* __restrict__ w,
                                               const float* __restrict__ bias,
                                               float* __restrict__ out) {
  constexpr int ID = OD * 2;
  constexpr int ID2 = ID * ID;
  __shared__ float wl[IC * 64];
  int bi = blockIdx.x;
  int chunk = bi % CHUNKS;
  int oc = (bi / CHUNKS) % OC;
  int b = bi / (CHUNKS * OC);
  for (int i = threadIdx.x; i < IC * 64; i += 256) wl[i] = w[oc * IC * 64 + i];
  __syncthreads();
  int s = chunk * 256 + threadIdx.x;
  if (s >= OD * OD * OD) return;
  int od = s / (OD * OD), oh = (s / OD) % OD, ow = s % OD;
  float acc = 0.f;
  for (int ic = 0; ic < IC; ++ic) {
    const float* ipb = in + (size_t)(b * IC + ic) * (ID * ID2);
    const float* wp = wl + ic * 64;
#pragma unroll
    for (int kd = 0; kd < 4; ++kd) {
      int id = od * 2 - 1 + kd;
      if ((unsigned)id < (unsigned)ID) {
#pragma unroll
        for (int kh = 0; kh < 4; ++kh) {
          int ih = oh * 2 - 1 + kh;
          if ((unsigned)ih < (unsigned)ID) {
            const float* rowp = ipb + id * ID2 + ih * ID;
#pragma unroll
            for (int kw = 0; kw < 4; ++kw) {
              int iw = ow * 2 - 1 + kw;
              if ((unsigned)iw < (unsigned)ID)
                acc = fmaf(rowp[iw], wp[kd * 16 + kh * 4 + kw], acc);
            }
          }
        }
      }
    }
  }
  acc += bias[oc];
  out[((size_t)(b * OC + oc) * OD + od) * (OD * OD) + oh * OD + ow] = fmaxf(acc, 0.f);
}

__global__ __launch_bounds__(256) void conv_t2(const float* __restrict__ in,
                                               const float* __restrict__ w,
                                               const float* __restrict__ bias,
                                               float* __restrict__ out) {
  __shared__ float patch[2][4864];
  __shared__ float wl[2][512];
  const int bi = blockIdx.x;
  const int od = bi & 15;
  const int ocg = (bi >> 4) & 7;
  const int b = bi >> 7;
  const int t = threadIdx.x;
  const int oh = t >> 4, ow = t & 15;
  int off[19];
#pragma unroll
  for (int n = 0; n < 19; ++n) {
    int idx = t + n * 256;
    off[n] = -1;
    if (idx < 4624) {
      int kd = idx / 1156;
      int r = idx - kd * 1156;
      int py = r / 34, px = r - py * 34;
      int id = od * 2 - 1 + kd;
      int ih = py - 1, iw = px - 1;
      if ((unsigned)id < 32u && (unsigned)ih < 32u && (unsigned)iw < 32u)
        off[n] = (b * 32) * 32768 + id * 1024 + ih * 32 + iw;
    }
  }
  const int wbase = (ocg * 8 + (t >> 6)) * 32 * 64 + (t & 63);
  const int wbase2 = (ocg * 8 + ((t + 256) >> 6)) * 32 * 64 + (t & 63);
#pragma unroll
  for (int n = 0; n < 19; ++n) patch[0][t + n * 256] = (off[n] >= 0) ? in[off[n]] : 0.f;
  wl[0][t] = w[wbase];
  wl[0][t + 256] = w[wbase2];
  __syncthreads();
  float acc[8];
#pragma unroll
  for (int o = 0; o < 8; ++o) acc[o] = 0.f;
  for (int ic = 0; ic < 32; ++ic) {
    const int buf = ic & 1;
    float rv[19], wr0 = 0.f, wr1 = 0.f;
    if (ic < 31) {
#pragma unroll
      for (int n = 0; n < 19; ++n)
        rv[n] = (off[n] >= 0) ? in[off[n] + (ic + 1) * 32768] : 0.f;
      wr0 = w[wbase + (ic + 1) * 64];
      wr1 = w[wbase2 + (ic + 1) * 64];
    }
    const float* pb = &patch[buf][0];
    const float* wb = &wl[buf][0];
#pragma unroll
    for (int kd = 0; kd < 4; ++kd)
#pragma unroll
      for (int kh = 0; kh < 4; ++kh) {
        const float* prow = pb + kd * 1156 + (oh * 2 + kh) * 34 + ow * 2;
#pragma unroll
        for (int kw = 0; kw < 4; ++kw) {
          float iv = prow[kw];
          int tap = kd * 16 + kh * 4 + kw;
#pragma unroll
          for (int o = 0; o < 8; ++o) acc[o] = fmaf(iv, wb[o * 64 + tap], acc[o]);
        }
      }
    __syncthreads();
    if (ic < 31) {
#pragma unroll
      for (int n = 0; n < 19; ++n) patch[buf ^ 1][t + n * 256] = rv[n];
      wl[buf ^ 1][t] = wr0;
      wl[buf ^ 1][t + 256] = wr1;
    }
    __syncthreads();
  }
#pragma unroll
  for (int o = 0; o < 8; ++o) {
    int oc = ocg * 8 + o;
    out[(((size_t)(b * 64 + oc) * 16 + od) * 16 + oh) * 16 + ow] =
        fmaxf(acc[o] + bias[oc], 0.f);
  }
}

__global__ __launch_bounds__(256) void conv_t3(const float* __restrict__ in,
                                               const float* __restrict__ w,
                                               const float* __restrict__ bias,
                                               float* __restrict__ out) {
  __shared__ float patch[2][3328];
  __shared__ float wl[2][256];
  const int bi = blockIdx.x;
  const int ocg = bi & 31;
  const int odg = (bi >> 5) & 1;
  const int b = bi >> 6;
  const int t = threadIdx.x;
  const int od_l = t >> 6;
  const int oh = (t >> 3) & 7, ow = t & 7;
  int off[13];
#pragma unroll
  for (int n = 0; n < 13; ++n) {
    int idx = t + n * 256;
    off[n] = -1;
    if (idx < 3240) {
      int s = idx / 324;
      int r = idx - s * 324;
      int py = r / 18, px = r - py * 18;
      int id = odg * 8 - 1 + s;
      int ih = py - 1, iw = px - 1;
      if ((unsigned)id < 16u && (unsigned)ih < 16u && (unsigned)iw < 16u)
        off[n] = (b * 64) * 4096 + id * 256 + ih * 16 + iw;
    }
  }
  const int wbase = (ocg * 4 + (t >> 6)) * 64 * 64 + (t & 63);
#pragma unroll
  for (int n = 0; n < 13; ++n) patch[0][t + n * 256] = (off[n] >= 0) ? in[off[n]] : 0.f;
  wl[0][t] = w[wbase];
  __syncthreads();
  float acc[4];
#pragma unroll
  for (int o = 0; o < 4; ++o) acc[o] = 0.f;
  for (int ic = 0; ic < 64; ++ic) {
    const int buf = ic & 1;
    float rv[13], wr0 = 0.f;
    if (ic < 63) {
#pragma unroll
      for (int n = 0; n < 13; ++n)
        rv[n] = (off[n] >= 0) ? in[off[n] + (ic + 1) * 4096] : 0.f;
      wr0 = w[wbase + (ic + 1) * 64];
    }
    const float* pb = &patch[buf][0];
    const float* wb = &wl[buf][0];
#pragma unroll
    for (int kd = 0; kd < 4; ++kd) {
      int s = od_l * 2 + kd;
#pragma unroll
      for (int kh = 0; kh < 4; ++kh) {
        const float* prow = pb + s * 324 + (oh * 2 + kh) * 18 + ow * 2;
#pragma unroll
        for (int kw = 0; kw < 4; ++kw) {
          float iv = prow[kw];
          int tap = kd * 16 + kh * 4 + kw;
#pragma unroll
          for (int o = 0; o < 4; ++o) acc[o] = fmaf(iv, wb[o * 64 + tap], acc[o]);
        }
      }
    }
    __syncthreads();
    if (ic < 63) {
#pragma unroll
      for (int n = 0; n < 13; ++n) patch[buf ^ 1][t + n * 256] = rv[n];
      wl[buf ^ 1][t] = wr0;
    }
    __syncthreads();
  }
  int od = odg * 4 + od_l;
#pragma unroll
  for (int o = 0; o < 4; ++o) {
    int oc = ocg * 4 + o;
    out[(((size_t)(b * 128 + oc) * 8 + od) * 8 + oh) * 8 + ow] =
        fmaxf(acc[o] + bias[oc], 0.f);
  }
}

__global__ __launch_bounds__(64) void conv_v2(const float* __restrict__ in,
                                              const float* __restrict__ w,
                                              const float* __restrict__ bias,
                                              float* __restrict__ out) {
  constexpr int IC = 128, OD = 4, ID = 8, ID2 = 64;
  __shared__ float wl[IC * 64];
  int oc = blockIdx.x % 256;
  int b = blockIdx.x / 256;
  for (int i = threadIdx.x; i < IC * 64; i += 64) wl[i] = w[oc * IC * 64 + i];
  __syncthreads();
  int s = threadIdx.x;
  int od = s >> 4, oh = (s >> 2) & 3, ow = s & 3;
  float acc = 0.f;
  for (int ic = 0; ic < IC; ++ic) {
    const float* ipb = in + (size_t)(b * IC + ic) * (ID * ID2);
    const float* wp = wl + ic * 64;
#pragma unroll
    for (int kd = 0; kd < 4; ++kd) {
      int id = od * 2 - 1 + kd;
      if ((unsigned)id < (unsigned)ID) {
#pragma unroll
        for (int kh = 0; kh < 4; ++kh) {
          int ih = oh * 2 - 1 + kh;
          if ((unsigned)ih < (unsigned)ID) {
            const float* rowp = ipb + id * ID2 + ih * ID;
#pragma unroll
            for (int kw = 0; kw < 4; ++kw) {
              int iw = ow * 2 - 1 + kw;
              if ((unsigned)iw < (unsigned)ID)
                acc = fmaf(rowp[iw], wp[kd * 16 + kh * 4 + kw], acc);
            }
          }
        }
      }
    }
  }
  acc += bias[oc];
  out[((size_t)(b * 256 + oc) * OD + od) * 16 + oh * 4 + ow] = fmaxf(acc, 0.f);
}

__global__ __launch_bounds__(256) void conv_v3(const float* __restrict__ in,
                                               const float* __restrict__ w,
                                               const float* __restrict__ bias,
                                               float* __restrict__ codes) {
  __shared__ float inl[256 * 64];
  int b = blockIdx.x >> 3;
  int ocg = blockIdx.x & 7;
  for (int i = threadIdx.x; i < 256 * 64; i += 256) inl[i] = in[b * 256 * 64 + i];
  __syncthreads();
  int oc = ocg * 32 + (threadIdx.x >> 3);
  int s = threadIdx.x & 7;
  int od = s >> 2, oh = (s >> 1) & 1, ow = s & 1;
  const float* wp = w + (size_t)oc * 256 * 64;
  float acc = 0.f;
  for (int ic = 0; ic < 256; ++ic) {
    const float* ib = inl + ic * 64;
    const float* wb = wp + ic * 64;
#pragma unroll
    for (int kd = 0; kd < 4; ++kd) {
      int id = od * 2 - 1 + kd;
      if ((unsigned)id < 4u) {
#pragma unroll
        for (int kh = 0; kh < 4; ++kh) {
          int ih = oh * 2 - 1 + kh;
          if ((unsigned)ih < 4u) {
#pragma unroll
            for (int kw = 0; kw < 4; ++kw) {
              int iw = ow * 2 - 1 + kw;
              if ((unsigned)iw < 4u)
                acc = fmaf(ib[id * 16 + ih * 4 + iw], wb[kd * 16 + kh * 4 + kw], acc);
            }
          }
        }
      }
    }
  }
  acc += bias[oc];
  codes[(b * 8 + s) * 256 + oc] = fmaxf(acc, 0.f);
}

// ---------------- coherent access helpers (relaxed, agent scope) ----------------
// Per-access coherence: bypasses local caches to the device coherence point
// WITHOUT emitting buffer_inv / buffer_wbl2 (those come only from acq/rel fences).
__device__ __forceinline__ float cload(const float* p) {
  return __hip_atomic_load(p, __ATOMIC_RELAXED, __HIP_MEMORY_SCOPE_AGENT);
}
__device__ __forceinline__ void cstore(float* p, float v) {
  __hip_atomic_store(p, v, __ATOMIC_RELAXED, __HIP_MEMORY_SCOPE_AGENT);
}

// ---------------- fence-free 8-WG barrier (monotonic count + flag) ----------------
// __syncthreads drains vmcnt per wave (compiler-emitted s_waitcnt before
// s_barrier), so all coherent stores are complete before the arrive add.
__device__ __forceinline__ void gbar(int* bar, int e) {
  __syncthreads();
  if (threadIdx.x == 0) {
    int prev =
        __hip_atomic_fetch_add(&bar[0], 1, __ATOMIC_RELAXED, __HIP_MEMORY_SCOPE_AGENT);
    if (prev == 8 * e - 1) {
      __hip_atomic_store(&bar[32], e, __ATOMIC_RELAXED, __HIP_MEMORY_SCOPE_AGENT);
    } else {
      while (__hip_atomic_load(&bar[32], __ATOMIC_RELAXED, __HIP_MEMORY_SCOPE_AGENT) < e)
        __builtin_amdgcn_s_sleep(1);
    }
  }
  __syncthreads();
}

// ---------------- LayerNorm: one wave per row ----------------
__device__ __forceinline__ void ln_rows(const float (*sxx)[256], float (*shh)[256],
                                        const float* __restrict__ gsc,
                                        const float* __restrict__ gbi, int NJ) {
  int wv = threadIdx.x >> 6, lane = threadIdx.x & 63;
  if (wv < NJ) {
    float4 xv = *(const float4*)&sxx[wv][lane * 4];
    float s = xv.x + xv.y + xv.z + xv.w;
#pragma unroll
    for (int off = 32; off >= 1; off >>= 1) s += __shfl_xor(s, off);
    float mean = s * (1.f / 256.f);
    float d0 = xv.x - mean, d1 = xv.y - mean, d2 = xv.z - mean, d3 = xv.w - mean;
    float v = d0 * d0 + d1 * d1 + d2 * d2 + d3 * d3;
#pragma unroll
    for (int off = 32; off >= 1; off >>= 1) v += __shfl_xor(v, off);
    float rsd = 1.f / sqrtf(v * (1.f / 256.f) + 1e-5f);
    float4 s4 = *(const float4*)&gsc[lane * 4];
    float4 b4 = *(const float4*)&gbi[lane * 4];
    float4 hv;
    hv.x = d0 * rsd * s4.x + b4.x;
    hv.y = d1 * rsd * s4.y + b4.y;
    hv.z = d2 * rsd * s4.z + b4.z;
    hv.w = d3 * rsd * s4.w + b4.w;
    *(float4*)&shh[wv][lane * 4] = hv;
  }
}

// ---------------- per-chunk transformer layers ----------------
template <int PRE, int NJ>
__device__ void run_chunk(int b, int w, int ti, int rbase,
                          const float* __restrict__ codes,
                          const float* __restrict__ tok_emb,
                          const float* __restrict__ pos_emb,
                          const float* __restrict__ Wqkv, const float* __restrict__ Wo,
                          const float* __restrict__ ln1s, const float* __restrict__ ln1b,
                          const float* __restrict__ ln2s, const float* __restrict__ ln2b,
                          const float* __restrict__ Wff1, const float* __restrict__ bff1,
                          const float* __restrict__ Wff2, const float* __restrict__ bff2,
                          float* __restrict__ Kc, float* __restrict__ Vc,
                          float* __restrict__ gq, float* __restrict__ gf1,
                          float* __restrict__ gx, float (*sx)[256], float (*sh)[256],
                          float (*f1b)[1024], float* sq, float* sc, float* part,
                          const int (*sSeq)[32], const int (*sPtr)[40], int* bar,
                          int& eb) {
  const int t = threadIdx.x;
  // ---- embedding (local, redundant per WG) ----
  for (int i = t; i < NJ * 256; i += 512) {
    int j = i >> 8, c = i & 255;
    int row = PRE ? (rbase + j) : (8 + ti);
    float v;
    if (PRE)
      v = (row < 8) ? codes[(b * 8 + row) * 256 + c] : tok_emb[256 + c];  // START=1
    else
      v = tok_emb[sSeq[j][ti] * 256 + c];
    sx[j][c] = v + pos_emb[row * 256 + c];
  }
  __syncthreads();

  for (int l = 0; l < 4; ++l) {
    // ---- LN1 ----
    ln_rows(sx, sh, ln1s + l * 256, ln1b + l * 256, NJ);
    __syncthreads();
    // ---- QKV slice: thread-per-(col,row), cols w*96..w*96+95 of 768 ----
    if (t < 96 * NJ) {
      int cl = t % 96, j = t / 96;
      int col = w * 96 + cl;
      const float* wp = Wqkv + (size_t)l * 196608 + col;
      float acc = 0.f;
#pragma unroll 8
      for (int k = 0; k < 256; ++k) acc = fmaf(sh[j][k], wp[(size_t)k * 768], acc);
      int row = PRE ? (rbase + j) : (8 + ti);
      int slot = PRE ? (b * 5) : (b * 5 + j);
      if (col < 256)
        cstore(&gq[(b * 5 + j) * 256 + col], acc);
      else if (col < 512)
        cstore(&Kc[((size_t)(l * 40 + slot) * 40 + row) * 256 + col - 256], acc);
      else
        cstore(&Vc[((size_t)(l * 40 + slot) * 40 + row) * 256 + col - 512], acc);
    }
    gbar(bar, ++eb);
    // ---- attention: WG w = head w (touches only cols w*32 of gq) ----
    if (t < NJ * 32) sq[t] = cload(&gq[(b * 5 + (t >> 5)) * 256 + w * 32 + (t & 31)]);
    __syncthreads();
    if (t < NJ * 40) {
      int j = t / 40, jj = t - j * 40;
      int rowj = PRE ? (rbase + j) : (8 + ti);
      if (jj <= rowj) {
        const float* kp =
            Kc + ((size_t)(l * 40 + sPtr[j][jj]) * 40 + jj) * 256 + w * 32;
        float s = 0.f;
#pragma unroll
        for (int d = 0; d < 32; d += 4) {
          float4 k4 = *(const float4*)(kp + d);
          s = fmaf(sq[j * 32 + d], k4.x,
                   fmaf(sq[j * 32 + d + 1], k4.y,
                        fmaf(sq[j * 32 + d + 2], k4.z,
                             fmaf(sq[j * 32 + d + 3], k4.w, s))));
        }
        sc[j * 40 + jj] = s * 0.17677669529663687f;  // 1/sqrt(32)
      }
    }
    __syncthreads();
    if (t < NJ) {
      int rowj = PRE ? (rbase + t) : (8 + ti);
      float m = -3.4e38f;
      for (int jj = 0; jj <= rowj; ++jj) m = fmaxf(m, sc[t * 40 + jj]);
      float su = 0.f;
      for (int jj = 0; jj <= rowj; ++jj) su += expf(sc[t * 40 + jj] - m);
      for (int jj = 0; jj <= rowj; ++jj) sc[t * 40 + jj] = expf(sc[t * 40 + jj] - m) / su;
    }
    __syncthreads();
    if (t < NJ * 32) {
      int j = t >> 5, d = t & 31;
      int rowj = PRE ? (rbase + j) : (8 + ti);
      float o = 0.f;
      for (int jj = 0; jj <= rowj; ++jj)
        o = fmaf(sc[j * 40 + jj],
                 Vc[((size_t)(l * 40 + sPtr[j][jj]) * 40 + jj) * 256 + w * 32 + d], o);
      cstore(&gq[(b * 5 + j) * 256 + w * 32 + d], o);
    }
    gbar(bar, ++eb);
    // ---- Wo FULL (redundant per WG; weights L2-shared per XCD) + residual ----
    for (int i = t; i < NJ * 256; i += 512)
      sh[i >> 8][i & 255] = cload(&gq[(b * 5 + (i >> 8)) * 256 + (i & 255)]);
    __syncthreads();
    {
      int c = t & 255, jh = t >> 8;
      const int R0 = (NJ + 1) / 2;
      int jbase = jh ? R0 : 0;
      int nr = jh ? (NJ - R0) : R0;
      int j1 = jbase + (nr > 1 ? 1 : 0), j2 = jbase + (nr > 2 ? 2 : 0);
      float a0 = 0.f, a1 = 0.f, a2 = 0.f;
      const float* wp = Wo + (size_t)l * 65536 + c;
#pragma unroll 4
      for (int k = 0; k < 256; ++k) {
        float wv = wp[(size_t)k * 256];
        a0 = fmaf(sh[jbase][k], wv, a0);
        a1 = fmaf(sh[j1][k], wv, a1);
        a2 = fmaf(sh[j2][k], wv, a2);
      }
      sx[jbase][c] += a0;
      if (nr > 1) sx[jbase + 1][c] += a1;
      if (nr > 2) sx[jbase + 2][c] += a2;
    }
    __syncthreads();
    // ---- LN2 ----
    ln_rows(sx, sh, ln2s + l * 256, ln2b + l * 256, NJ);
    __syncthreads();
    // ---- FF1 slice: cols w*128..w*128+127 of 1024 ----
    for (int job = t; job < 128 * NJ; job += 512) {
      int cl = job & 127, j = job >> 7;
      int col = w * 128 + cl;
      const float* wp = Wff1 + (size_t)l * 262144 + col;
      float acc = 0.f;
#pragma unroll 8
      for (int k = 0; k < 256; ++k) acc = fmaf(sh[j][k], wp[(size_t)k * 1024], acc);
      cstore(&gf1[(b * 5 + j) * 1024 + col], fmaxf(acc + bff1[l * 1024 + col], 0.f));
    }
    gbar(bar, ++eb);
    // ---- FF2 slice: cols w*32, k=1024 (4-way k-split, LDS partials) ----
    for (int i = t; i < NJ * 1024; i += 512)
      f1b[i >> 10][i & 1023] = cload(&gf1[(b * 5 + (i >> 10)) * 1024 + (i & 1023)]);
    __syncthreads();
    for (int job = t; job < NJ * 128; job += 512) {
      int ks = job & 3, cl = (job >> 2) & 31, j = job >> 7;
      int col = w * 32 + cl;
      const float* wp = Wff2 + (size_t)l * 262144 + (size_t)(ks * 256) * 256 + col;
      const float* fp = &f1b[j][ks * 256];
      float acc = 0.f;
#pragma unroll 8
      for (int kk = 0; kk < 256; ++kk) acc = fmaf(fp[kk], wp[(size_t)kk * 256], acc);
      part[job] = acc;
    }
    __syncthreads();
    if (t < NJ * 32) {
      int cl = t & 31, j = t >> 5;
      int col = w * 32 + cl;
      int base = (j * 32 + cl) * 4;
      float s = part[base] + part[base + 1] + part[base + 2] + part[base + 3];
      cstore(&gx[(b * 5 + j) * 256 + col], sx[j][col] + s + bff2[l * 256 + col]);
    }
    gbar(bar, ++eb);
    for (int i = t; i < NJ * 256; i += 512)
      sx[i >> 8][i & 255] = cload(&gx[(b * 5 + (i >> 8)) * 256 + (i & 255)]);
    __syncthreads();
  }
}

// ---------------- persistent decode kernel ----------------
__global__ __launch_bounds__(512, 1) void k_dec(
    const float* __restrict__ codes, const float* __restrict__ tok_emb,
    const float* __restrict__ pos_emb, const float* __restrict__ Wqkv,
    const float* __restrict__ Wo, const float* __restrict__ ln1s,
    const float* __restrict__ ln1b, const float* __restrict__ ln2s,
    const float* __restrict__ ln2b, const float* __restrict__ Wff1,
    const float* __restrict__ bff1, const float* __restrict__ Wff2,
    const float* __restrict__ bff2, const float* __restrict__ hW1,
    const float* __restrict__ hb1, const float* __restrict__ hW2,
    const float* __restrict__ hb2, float* __restrict__ Kc, float* __restrict__ Vc,
    float* __restrict__ gq, float* __restrict__ gf1, float* __restrict__ gx,
    int* __restrict__ bars, float* __restrict__ out) {
  const int t = threadIdx.x;
  const int b = blockIdx.x >> 3;
  const int w = blockIdx.x & 7;
  int* bar = bars + b * 64;
  int eb = 0;

  __shared__ __align__(16) float sx[5][256];
  __shared__ __align__(16) float sh[5][256];
  __shared__ __align__(16) float f1b[5][1024];
  __shared__ float sq[160], sc[200], part[640];
  __shared__ __align__(16) float sLg[5][64];
  __shared__ int sSeq[5][32], sPtr[5][40];
  __shared__ float sLls[5];
  __shared__ float bmF[360];  // bdist 320 | bd 25 | nll 5 | rm 5 | rs 5
  __shared__ int bmI[400];    // osq 160 | opt 200 | bc 25 | nts 5 | oldx 5

  // ---- init replicated per-batch beam state ----
  for (int i = t; i < 160; i += 512) sSeq[i >> 5][i & 31] = ((i & 31) == 0) ? 1 : 0;
  for (int i = t; i < 200; i += 512) sPtr[i / 40][i % 40] = b * 5;  // leader
  if (t < 5) sLls[t] = (t == 0) ? 0.f : -100000.0f;
  __syncthreads();

  for (int ti = 0; ti < 31; ++ti) {
    const bool pre = (ti == 0);
    if (pre) {
      run_chunk<1, 5>(b, w, ti, 0, codes, tok_emb, pos_emb, Wqkv, Wo, ln1s, ln1b, ln2s,
                      ln2b, Wff1, bff1, Wff2, bff2, Kc, Vc, gq, gf1, gx, sx, sh, f1b,
                      sq, sc, part, sSeq, sPtr, bar, eb);
      run_chunk<1, 4>(b, w, ti, 5, codes, tok_emb, pos_emb, Wqkv, Wo, ln1s, ln1b, ln2s,
                      ln2b, Wff1, bff1, Wff2, bff2, Kc, Vc, gq, gf1, gx, sx, sh, f1b,
                      sq, sc, part, sSeq, sPtr, bar, eb);
    } else {
      run_chunk<0, 5>(b, w, ti, 0, codes, tok_emb, pos_emb, Wqkv, Wo, ln1s, ln1b, ln2s,
                      ln2b, Wff1, bff1, Wff2, bff2, Kc, Vc, gq, gf1, gx, sx, sh, f1b,
                      sq, sc, part, sSeq, sPtr, bar, eb);
    }
    // ---- head (FULL, redundant per WG; weights L2-shared per XCD) ----
    {
      const int NJH = pre ? 1 : 5;
      for (int job = t; job < 256 * NJH; job += 512) {
        int c = job & 255, j = job >> 8;
        int src = pre ? 3 : j;  // prefill chunk2: row 8 = local j 3
        const float* wp = hW1 + c;
        float acc = 0.f;
#pragma unroll 8
        for (int k = 0; k < 256; ++k) acc = fmaf(sx[src][k], wp[(size_t)k * 256], acc);
        f1b[j][c] = fmaxf(acc + hb1[c], 0.f);
      }
      __syncthreads();
      for (int job = t; job < 64 * NJH; job += 512) {
        int c = job & 63, j = job >> 6;
        const float* wp = hW2 + c;
        float acc = 0.f;
#pragma unroll 8
        for (int k = 0; k < 256; ++k) acc = fmaf(f1b[j][k], wp[(size_t)k * 64], acc);
        sLg[j][c] = acc + hb2[c];
      }
      __syncthreads();
      if (pre) {
        for (int i = t; i < 320; i += 512) {
          int j = i >> 6, c = i & 63;
          if (j > 0) sLg[j][c] = sLg[0][c];
        }
        __syncthreads();
      }
    }
    // ---- beam update (replicated per WG, exact tie semantics) ----
    {
      float* bdist = bmF;       // 320
      float* bd = bmF + 320;    // 25
      float* nll = bmF + 345;   // 5
      float* rm = bmF + 350;    // 5
      float* rs = bmF + 355;    // 5
      int* osq = bmI;           // 160
      int* opt = bmI + 160;     // 200
      int* bc = bmI + 360;      // 25
      int* nts = bmI + 385;     // 5
      int* oldx = bmI + 390;    // 5
      for (int i = t; i < 160; i += 512) osq[i] = sSeq[i >> 5][i & 31];
      for (int i = t; i < 200; i += 512) opt[i] = sPtr[i / 40][i % 40];
      __syncthreads();
      if (t < 5) {
        float m = -3.4e38f;
        for (int j = 0; j < 64; ++j) m = fmaxf(m, sLg[t][j]);
        float s = 0.f;
        for (int j = 0; j < 64; ++j) s += expf(sLg[t][j] - m);
        rm[t] = m;
        rs[t] = s;
      }
      __syncthreads();
      for (int i = t; i < 320; i += 512) {
        int r = i >> 6;
        bdist[i] = logf(expf(sLg[r][i & 63] - rm[r]) / rs[r] + 1e-8f);
      }
      __syncthreads();
      if (t < 5) {
        float pv = 3.4e38f;
        int pi = -1;
        for (int r = 0; r < 5; ++r) {
          float bv = -3.4e38f;
          int bi = -1;
          for (int j = 0; j < 64; ++j) {
            float v = bdist[t * 64 + j];
            bool lessprev = (v < pv) || (v == pv && j > pi);
            if (lessprev && v > bv) { bv = v; bi = j; }
          }
          bd[t * 5 + r] = bv;
          bc[t * 5 + r] = bi;
          pv = bv;
          pi = bi;
        }
      }
      __syncthreads();
      if (t == 0) {
        float pv = 3.4e38f;
        int pi = -1;
        for (int r = 0; r < 5; ++r) {
          float bv = -3.4e38f;
          int bi = -1;
          for (int idx = 0; idx < 25; ++idx) {
            int kb = idx / 5, jj = idx % 5;
            float v = bd[kb * 5 + jj] + sLls[kb];
            bool lessprev = (v < pv) || (v == pv && idx > pi);
            if (lessprev && v > bv) { bv = v; bi = idx; }
          }
          int kb = bi / 5, jj = bi % 5;
          int tok = bc[kb * 5 + jj];
          nts[r] = tok;
          oldx[r] = kb;
          nll[r] = (tok == 2) ? (bv - 100000.0f) : bv;
          pv = bv;
          pi = bi;
        }
      }
      __syncthreads();
      for (int i = t; i < 160; i += 512) {
        int bm = i >> 5, j2 = i & 31;
        int v = osq[oldx[bm] * 32 + j2];
        if (j2 == ti + 1) v = nts[bm];
        sSeq[bm][j2] = v;
      }
      int r1 = 8 + ti;
      for (int i = t; i < 200; i += 512) {
        int bm = i / 40, j2 = i % 40;
        sPtr[bm][j2] = (j2 <= r1) ? opt[oldx[bm] * 40 + j2] : (b * 5 + bm);
      }
      if (t < 5) sLls[t] = nll[t];
      __syncthreads();
    }
  }
  // ---- output: bseqs (40,32) as float, then blls (40,) ----
  if (w == 0) {
    for (int i = t; i < 160; i += 512) out[b * 160 + i] = (float)sSeq[i >> 5][i & 31];
    if (t < 5) out[1280 + b * 5 + t] = sLls[t];
  }
}

// ---------------- host ----------------
extern "C" void kernel_launch(void* const* d_in, const int* in_sizes, int n_in,
                              void* d_out, int out_size, void* d_ws, size_t ws_size,
                              hipStream_t stream) {
  const float* voxels = (const float*)d_in[0];
  const float* ck1 = (const float*)d_in[1];
  const float* cb1 = (const float*)d_in[2];
  const float* ck2 = (const float*)d_in[3];
  const float* cb2 = (const float*)d_in[4];
  const float* ck3 = (const float*)d_in[5];
  const float* cb3 = (const float*)d_in[6];
  const float* ck4 = (const float*)d_in[7];
  const float* cb4 = (const float*)d_in[8];
  const float* ck5 = (const float*)d_in[9];
  const float* cb5 = (const float*)d_in[10];
  const float* tok_emb = (const float*)d_in[11];
  const float* pos_emb = (const float*)d_in[12];
  const float* Wqkv = (const float*)d_in[13];
  const float* Wo = (const float*)d_in[14];
  const float* ln1s = (const float*)d_in[15];
  const float* ln1b = (const float*)d_in[16];
  const float* ln2s = (const float*)d_in[17];
  const float* ln2b = (const float*)d_in[18];
  const float* Wff1 = (const float*)d_in[19];
  const float* bff1 = (const float*)d_in[20];
  const float* Wff2 = (const float*)d_in[21];
  const float* bff2 = (const float*)d_in[22];
  const float* hW1 = (const float*)d_in[23];
  const float* hb1 = (const float*)d_in[24];
  const float* hW2 = (const float*)d_in[25];
  const float* hb2 = (const float*)d_in[26];

  float* ws = (float*)d_ws;
  // conv chain buffers
  float* c1 = ws;              // 8,388,608 f
  float* c2 = c1 + 8388608;    // 2,097,152 f
  float* c3 = c2 + 2097152;    //   524,288 f
  float* c4 = c3 + 524288;     //   131,072 f
  float* codes = c4 + 131072;  //    16,384 f  (end: 11,157,504)
  // K/V caches alias c1 (dead after conv_t2); per-dispatch acquire invalidates
  // stale conv lines at k_dec start, so normal cached K/V reads are safe.
  float* Kc = ws;            // 1,638,400 f
  float* Vc = Kc + 1638400;  // 1,638,400 f
  // cross-WG buffers + barriers: fresh region past codes (never conv-aliased)
  float* gq = codes + 16384;         // 10,240 f  [8][5][256]
  float* gf1 = gq + 10240;           // 40,960 f  [8][5][1024]
  float* gx = gf1 + 40960;           // 10,240 f  [8][5][256]
  int* bars = (int*)(gx + 10240);    // 512 i     [8][64]

  conv_v1<1, 32, 32, 128><<<8 * 32 * 128, 256, 0, stream>>>(voxels, ck1, cb1, c1);
  conv_t2<<<8 * 16 * 8, 256, 0, stream>>>(c1, ck2, cb2, c2);
  conv_t3<<<8 * 2 * 32, 256, 0, stream>>>(c2, ck3, cb3, c3);
  conv_v2<<<8 * 256, 64, 0, stream>>>(c3, ck4, cb4, c4);
  conv_v3<<<8 * 8, 256, 0, stream>>>(c4, ck5, cb5, codes);

  hipMemsetAsync(bars, 0, 512 * sizeof(int), stream);
  k_dec<<<64, 512, 0, stream>>>(codes, tok_emb, pos_emb, Wqkv, Wo, ln1s, ln1b, ln2s,
                                ln2b, Wff1, bff1, Wff2, bff2, hW1, hb1, hW2, hb2, Kc,
                                Vc, gq, gf1, gx, bars, (float*)d_out);
}

// Round 10
// 20165.654 us; speedup vs baseline: 1.0123x; 1.0123x over previous
//
#include <hip/hip_runtime.h>
#include <math.h>

// ---------------- model constants ----------------
// HD=256 NL=4 NH=8 DH=32 MP=8 MS=32 T=40 ES=64 BATCH=8 BEAMS=5 BB=40
// START=1 END=2 MIN_LL_PEN=-100000
// Decode: 8 groups (batch) x 8 WGs x 512 thr. Column-sliced GEMMs, cross-WG
// data via relaxed agent-scope atomics (per-access coherent, NO L2 inv/wb),
// fence-free monotonic barrier. Wo/head/beam computed redundantly per WG.

// ---------------- conv kernels (proven rounds 3-6, unchanged) ----------------
template <int IC, int OC, int OD, int CHUNKS>
__global__ __launch_bounds__(256) void conv_v1(const float* __restrict__ in,
                                               const float* __restrict__ w,
                                               const float* __restrict__ bias,
                                               float* __restrict__ out) {
  constexpr int ID = OD * 2;
  constexpr int ID2 = ID * ID;
  __shared__ float wl[IC * 64];
  int bi = blockIdx.x;
  int chunk = bi % CHUNKS;
  int oc = (bi / CHUNKS) % OC;
  int b = bi / (CHUNKS * OC);
  for (int i = threadIdx.x; i < IC * 64; i += 256) wl[i] = w[oc * IC * 64 + i];
  __syncthreads();
  int s = chunk * 256 + threadIdx.x;
  if (s >= OD * OD * OD) return;
  int od = s / (OD * OD), oh = (s / OD) % OD, ow = s % OD;
  float acc = 0.f;
  for (int ic = 0; ic < IC; ++ic) {
    const float* ipb = in + (size_t)(b * IC + ic) * (ID * ID2);
    const float* wp = wl + ic * 64;
#pragma unroll
    for (int kd = 0; kd < 4; ++kd) {
      int id = od * 2 - 1 + kd;
      if ((unsigned)id < (unsigned)ID) {
#pragma unroll
        for (int kh = 0; kh < 4; ++kh) {
          int ih = oh * 2 - 1 + kh;
          if ((unsigned)ih < (unsigned)ID) {
            const float* rowp = ipb + id * ID2 + ih * ID;
#pragma unroll
            for (int kw = 0; kw < 4; ++kw) {
              int iw = ow * 2 - 1 + kw;
              if ((unsigned)iw < (unsigned)ID)
                acc = fmaf(rowp[iw], wp[kd * 16 + kh * 4 + kw], acc);
            }
          }
        }
      }
    }
  }
  acc += bias[oc];
  out[((size_t)(b * OC + oc) * OD + od) * (OD * OD) + oh * OD + ow] = fmaxf(acc, 0.f);
}

__global__ __launch_bounds__(256) void conv_t2(const float* __restrict__ in,
                                               const float* __restrict__ w,
                                               const float* __restrict__ bias,
                                               float* __restrict__ out) {
  __shared__ float patch[2][4864];
  __shared__ float wl[2][512];
  const int bi = blockIdx.x;
  const int od = bi & 15;
  const int ocg = (bi >> 4) & 7;
  const int b = bi >> 7;
  const int t = threadIdx.x;
  const int oh = t >> 4, ow = t & 15;
  int off[19];
#pragma unroll
  for (int n = 0; n < 19; ++n) {
    int idx = t + n * 256;
    off[n] = -1;
    if (idx < 4624) {
      int kd = idx / 1156;
      int r = idx - kd * 1156;
      int py = r / 34, px = r - py * 34;
      int id = od * 2 - 1 + kd;
      int ih = py - 1, iw = px - 1;
      if ((unsigned)id < 32u && (unsigned)ih < 32u && (unsigned)iw < 32u)
        off[n] = (b * 32) * 32768 + id * 1024 + ih * 32 + iw;
    }
  }
  const int wbase = (ocg * 8 + (t >> 6)) * 32 * 64 + (t & 63);
  const int wbase2 = (ocg * 8 + ((t + 256) >> 6)) * 32 * 64 + (t & 63);
#pragma unroll
  for (int n = 0; n < 19; ++n) patch[0][t + n * 256] = (off[n] >= 0) ? in[off[n]] : 0.f;
  wl[0][t] = w[wbase];
  wl[0][t + 256] = w[wbase2];
  __syncthreads();
  float acc[8];
#pragma unroll
  for (int o = 0; o < 8; ++o) acc[o] = 0.f;
  for (int ic = 0; ic < 32; ++ic) {
    const int buf = ic & 1;
    float rv[19], wr0 = 0.f, wr1 = 0.f;
    if (ic < 31) {
#pragma unroll
      for (int n = 0; n < 19; ++n)
        rv[n] = (off[n] >= 0) ? in[off[n] + (ic + 1) * 32768] : 0.f;
      wr0 = w[wbase + (ic + 1) * 64];
      wr1 = w[wbase2 + (ic + 1) * 64];
    }
    const float* pb = &patch[buf][0];
    const float* wb = &wl[buf][0];
#pragma unroll
    for (int kd = 0; kd < 4; ++kd)
#pragma unroll
      for (int kh = 0; kh < 4; ++kh) {
        const float* prow = pb + kd * 1156 + (oh * 2 + kh) * 34 + ow * 2;
#pragma unroll
        for (int kw = 0; kw < 4; ++kw) {
          float iv = prow[kw];
          int tap = kd * 16 + kh * 4 + kw;
#pragma unroll
          for (int o = 0; o < 8; ++o) acc[o] = fmaf(iv, wb[o * 64 + tap], acc[o]);
        }
      }
    __syncthreads();
    if (ic < 31) {
#pragma unroll
      for (int n = 0; n < 19; ++n) patch[buf ^ 1][t + n * 256] = rv[n];
      wl[buf ^ 1][t] = wr0;
      wl[buf ^ 1][t + 256] = wr1;
    }
    __syncthreads();
  }
#pragma unroll
  for (int o = 0; o < 8; ++o) {
    int oc = ocg * 8 + o;
    out[(((size_t)(b * 64 + oc) * 16 + od) * 16 + oh) * 16 + ow] =
        fmaxf(acc[o] + bias[oc], 0.f);
  }
}

__global__ __launch_bounds__(256) void conv_t3(const float* __restrict__ in,
                                               const float* __restrict__ w,
                                               const float* __restrict__ bias,
                                               float* __restrict__ out) {
  __shared__ float patch[2][3328];
  __shared__ float wl[2][256];
  const int bi = blockIdx.x;
  const int ocg = bi & 31;
  const int odg = (bi >> 5) & 1;
  const int b = bi >> 6;
  const int t = threadIdx.x;
  const int od_l = t >> 6;
  const int oh = (t >> 3) & 7, ow = t & 7;
  int off[13];
#pragma unroll
  for (int n = 0; n < 13; ++n) {
    int idx = t + n * 256;
    off[n] = -1;
    if (idx < 3240) {
      int s = idx / 324;
      int r = idx - s * 324;
      int py = r / 18, px = r - py * 18;
      int id = odg * 8 - 1 + s;
      int ih = py - 1, iw = px - 1;
      if ((unsigned)id < 16u && (unsigned)ih < 16u && (unsigned)iw < 16u)
        off[n] = (b * 64) * 4096 + id * 256 + ih * 16 + iw;
    }
  }
  const int wbase = (ocg * 4 + (t >> 6)) * 64 * 64 + (t & 63);
#pragma unroll
  for (int n = 0; n < 13; ++n) patch[0][t + n * 256] = (off[n] >= 0) ? in[off[n]] : 0.f;
  wl[0][t] = w[wbase];
  __syncthreads();
  float acc[4];
#pragma unroll
  for (int o = 0; o < 4; ++o) acc[o] = 0.f;
  for (int ic = 0; ic < 64; ++ic) {
    const int buf = ic & 1;
    float rv[13], wr0 = 0.f;
    if (ic < 63) {
#pragma unroll
      for (int n = 0; n < 13; ++n)
        rv[n] = (off[n] >= 0) ? in[off[n] + (ic + 1) * 4096] : 0.f;
      wr0 = w[wbase + (ic + 1) * 64];
    }
    const float* pb = &patch[buf][0];
    const float* wb = &wl[buf][0];
#pragma unroll
    for (int kd = 0; kd < 4; ++kd) {
      int s = od_l * 2 + kd;
#pragma unroll
      for (int kh = 0; kh < 4; ++kh) {
        const float* prow = pb + s * 324 + (oh * 2 + kh) * 18 + ow * 2;
#pragma unroll
        for (int kw = 0; kw < 4; ++kw) {
          float iv = prow[kw];
          int tap = kd * 16 + kh * 4 + kw;
#pragma unroll
          for (int o = 0; o < 4; ++o) acc[o] = fmaf(iv, wb[o * 64 + tap], acc[o]);
        }
      }
    }
    __syncthreads();
    if (ic < 63) {
#pragma unroll
      for (int n = 0; n < 13; ++n) patch[buf ^ 1][t + n * 256] = rv[n];
      wl[buf ^ 1][t] = wr0;
    }
    __syncthreads();
  }
  int od = odg * 4 + od_l;
#pragma unroll
  for (int o = 0; o < 4; ++o) {
    int oc = ocg * 4 + o;
    out[(((size_t)(b * 128 + oc) * 8 + od) * 8 + oh) * 8 + ow] =
        fmaxf(acc[o] + bias[oc], 0.f);
  }
}

__global__ __launch_bounds__(64) void conv_v2(const float* __restrict__ in,
                                              const float* __restrict__ w,
                                              const float* __restrict__ bias,
                                              float* __restrict__ out) {
  constexpr int IC = 128, OD = 4, ID = 8, ID2 = 64;
  __shared__ float wl[IC * 64];
  int oc = blockIdx.x % 256;
  int b = blockIdx.x / 256;
  for (int i = threadIdx.x; i < IC * 64; i += 64) wl[i] = w[oc * IC * 64 + i];
  __syncthreads();
  int s = threadIdx.x;
  int od = s >> 4, oh = (s >> 2) & 3, ow = s & 3;
  float acc = 0.f;
  for (int ic = 0; ic < IC; ++ic) {
    const float* ipb = in + (size_t)(b * IC + ic) * (ID * ID2);
    const float* wp = wl + ic * 64;
#pragma unroll
    for (int kd = 0; kd < 4; ++kd) {
      int id = od * 2 - 1 + kd;
      if ((unsigned)id < (unsigned)ID) {
#pragma unroll
        for (int kh = 0; kh < 4; ++kh) {
          int ih = oh * 2 - 1 + kh;
          if ((unsigned)ih < (unsigned)ID) {
            const float* rowp = ipb + id * ID2 + ih * ID;
#pragma unroll
            for (int kw = 0; kw < 4; ++kw) {
              int iw = ow * 2 - 1 + kw;
              if ((unsigned)iw < (unsigned)ID)
                acc = fmaf(rowp[iw], wp[kd * 16 + kh * 4 + kw], acc);
            }
          }
        }
      }
    }
  }
  acc += bias[oc];
  out[((size_t)(b * 256 + oc) * OD + od) * 16 + oh * 4 + ow] = fmaxf(acc, 0.f);
}

__global__ __launch_bounds__(256) void conv_v3(const float* __restrict__ in,
                                               const float* __restrict__ w,
                                               const float* __restrict__ bias,
                                               float* __restrict__ codes) {
  __shared__ float inl[256 * 64];
  int b = blockIdx.x >> 3;
  int ocg = blockIdx.x & 7;
  for (int i = threadIdx.x; i < 256 * 64; i += 256) inl[i] = in[b * 256 * 64 + i];
  __syncthreads();
  int oc = ocg * 32 + (threadIdx.x >> 3);
  int s = threadIdx.x & 7;
  int od = s >> 2, oh = (s >> 1) & 1, ow = s & 1;
  const float* wp = w + (size_t)oc * 256 * 64;
  float acc = 0.f;
  for (int ic = 0; ic < 256; ++ic) {
    const float* ib = inl + ic * 64;
    const float* wb = wp + ic * 64;
#pragma unroll
    for (int kd = 0; kd < 4; ++kd) {
      int id = od * 2 - 1 + kd;
      if ((unsigned)id < 4u) {
#pragma unroll
        for (int kh = 0; kh < 4; ++kh) {
          int ih = oh * 2 - 1 + kh;
          if ((unsigned)ih < 4u) {
#pragma unroll
            for (int kw = 0; kw < 4; ++kw) {
              int iw = ow * 2 - 1 + kw;
              if ((unsigned)iw < 4u)
                acc = fmaf(ib[id * 16 + ih * 4 + iw], wb[kd * 16 + kh * 4 + kw], acc);
            }
          }
        }
      }
    }
  }
  acc += bias[oc];
  codes[(b * 8 + s) * 256 + oc] = fmaxf(acc, 0.f);
}

// ---------------- coherent access helpers (relaxed, agent scope) ----------------
// Per-access coherence: bypasses local caches to the device coherence point
// WITHOUT emitting buffer_inv / buffer_wbl2 (those come only from acq/rel fences).
__device__ __forceinline__ float cload(const float* p) {
  return __hip_atomic_load(p, __ATOMIC_RELAXED, __HIP_MEMORY_SCOPE_AGENT);
}
__device__ __forceinline__ void cstore(float* p, float v) {
  __hip_atomic_store(p, v, __ATOMIC_RELAXED, __HIP_MEMORY_SCOPE_AGENT);
}

// ---------------- fence-free 8-WG barrier (monotonic count + flag) ----------------
// __syncthreads drains vmcnt per wave (compiler-emitted s_waitcnt before
// s_barrier), so all coherent stores are complete before the arrive add.
__device__ __forceinline__ void gbar(int* bar, int e) {
  __syncthreads();
  if (threadIdx.x == 0) {
    int prev =
        __hip_atomic_fetch_add(&bar[0], 1, __ATOMIC_RELAXED, __HIP_MEMORY_SCOPE_AGENT);
    if (prev == 8 * e - 1) {
      __hip_atomic_store(&bar[32], e, __ATOMIC_RELAXED, __HIP_MEMORY_SCOPE_AGENT);
    } else {
      while (__hip_atomic_load(&bar[32], __ATOMIC_RELAXED, __HIP_MEMORY_SCOPE_AGENT) < e)
        __builtin_amdgcn_s_sleep(1);
    }
  }
  __syncthreads();
}

// ---------------- LayerNorm: one wave per row ----------------
__device__ __forceinline__ void ln_rows(const float (*sxx)[256], float (*shh)[256],
                                        const float* __restrict__ gsc,
                                        const float* __restrict__ gbi, int NJ) {
  int wv = threadIdx.x >> 6, lane = threadIdx.x & 63;
  if (wv < NJ) {
    float4 xv = *(const float4*)&sxx[wv][lane * 4];
    float s = xv.x + xv.y + xv.z + xv.w;
#pragma unroll
    for (int off = 32; off >= 1; off >>= 1) s += __shfl_xor(s, off);
    float mean = s * (1.f / 256.f);
    float d0 = xv.x - mean, d1 = xv.y - mean, d2 = xv.z - mean, d3 = xv.w - mean;
    float v = d0 * d0 + d1 * d1 + d2 * d2 + d3 * d3;
#pragma unroll
    for (int off = 32; off >= 1; off >>= 1) v += __shfl_xor(v, off);
    float rsd = 1.f / sqrtf(v * (1.f / 256.f) + 1e-5f);
    float4 s4 = *(const float4*)&gsc[lane * 4];
    float4 b4 = *(const float4*)&gbi[lane * 4];
    float4 hv;
    hv.x = d0 * rsd * s4.x + b4.x;
    hv.y = d1 * rsd * s4.y + b4.y;
    hv.z = d2 * rsd * s4.z + b4.z;
    hv.w = d3 * rsd * s4.w + b4.w;
    *(float4*)&shh[wv][lane * 4] = hv;
  }
}

// ---------------- per-chunk transformer layers ----------------
template <int PRE, int NJ>
__device__ void run_chunk(int b, int w, int ti, int rbase,
                          const float* __restrict__ codes,
                          const float* __restrict__ tok_emb,
                          const float* __restrict__ pos_emb,
                          const float* __restrict__ Wqkv, const float* __restrict__ Wo,
                          const float* __restrict__ ln1s, const float* __restrict__ ln1b,
                          const float* __restrict__ ln2s, const float* __restrict__ ln2b,
                          const float* __restrict__ Wff1, const float* __restrict__ bff1,
                          const float* __restrict__ Wff2, const float* __restrict__ bff2,
                          float* __restrict__ Kc, float* __restrict__ Vc,
                          float* __restrict__ gq, float* __restrict__ gf1,
                          float* __restrict__ gx, float (*sx)[256], float (*sh)[256],
                          float (*f1b)[1024], float* sq, float* sc, float* part,
                          const int (*sSeq)[32], const int (*sPtr)[40], int* bar,
                          int& eb) {
  const int t = threadIdx.x;
  // ---- embedding (local, redundant per WG) ----
  for (int i = t; i < NJ * 256; i += 512) {
    int j = i >> 8, c = i & 255;
    int row = PRE ? (rbase + j) : (8 + ti);
    float v;
    if (PRE)
      v = (row < 8) ? codes[(b * 8 + row) * 256 + c] : tok_emb[256 + c];  // START=1
    else
      v = tok_emb[sSeq[j][ti] * 256 + c];
    sx[j][c] = v + pos_emb[row * 256 + c];
  }
  __syncthreads();

  for (int l = 0; l < 4; ++l) {
    // ---- LN1 ----
    ln_rows(sx, sh, ln1s + l * 256, ln1b + l * 256, NJ);
    __syncthreads();
    // ---- QKV slice: thread-per-(col,row), cols w*96..w*96+95 of 768 ----
    if (t < 96 * NJ) {
      int cl = t % 96, j = t / 96;
      int col = w * 96 + cl;
      const float* wp = Wqkv + (size_t)l * 196608 + col;
      float acc = 0.f;
#pragma unroll 8
      for (int k = 0; k < 256; ++k) acc = fmaf(sh[j][k], wp[(size_t)k * 768], acc);
      int row = PRE ? (rbase + j) : (8 + ti);
      int slot = PRE ? (b * 5) : (b * 5 + j);
      if (col < 256)
        cstore(&gq[(b * 5 + j) * 256 + col], acc);
      else if (col < 512)
        cstore(&Kc[((size_t)(l * 40 + slot) * 40 + row) * 256 + col - 256], acc);
      else
        cstore(&Vc[((size_t)(l * 40 + slot) * 40 + row) * 256 + col - 512], acc);
    }
    gbar(bar, ++eb);
    // ---- attention: WG w = head w (touches only cols w*32 of gq) ----
    if (t < NJ * 32) sq[t] = cload(&gq[(b * 5 + (t >> 5)) * 256 + w * 32 + (t & 31)]);
    __syncthreads();
    if (t < NJ * 40) {
      int j = t / 40, jj = t - j * 40;
      int rowj = PRE ? (rbase + j) : (8 + ti);
      if (jj <= rowj) {
        const float* kp =
            Kc + ((size_t)(l * 40 + sPtr[j][jj]) * 40 + jj) * 256 + w * 32;
        float s = 0.f;
#pragma unroll
        for (int d = 0; d < 32; d += 4) {
          float4 k4 = *(const float4*)(kp + d);
          s = fmaf(sq[j * 32 + d], k4.x,
                   fmaf(sq[j * 32 + d + 1], k4.y,
                        fmaf(sq[j * 32 + d + 2], k4.z,
                             fmaf(sq[j * 32 + d + 3], k4.w, s))));
        }
        sc[j * 40 + jj] = s * 0.17677669529663687f;  // 1/sqrt(32)
      }
    }
    __syncthreads();
    if (t < NJ) {
      int rowj = PRE ? (rbase + t) : (8 + ti);
      float m = -3.4e38f;
      for (int jj = 0; jj <= rowj; ++jj) m = fmaxf(m, sc[t * 40 + jj]);
      float su = 0.f;
      for (int jj = 0; jj <= rowj; ++jj) su += expf(sc[t * 40 + jj] - m);
      for (int jj = 0; jj <= rowj; ++jj) sc[t * 40 + jj] = expf(sc[t * 40 + jj] - m) / su;
    }
    __syncthreads();
    if (t < NJ * 32) {
      int j = t >> 5, d = t & 31;
      int rowj = PRE ? (rbase + j) : (8 + ti);
      float o = 0.f;
      for (int jj = 0; jj <= rowj; ++jj)
        o = fmaf(sc[j * 40 + jj],
                 Vc[((size_t)(l * 40 + sPtr[j][jj]) * 40 + jj) * 256 + w * 32 + d], o);
      cstore(&gq[(b * 5 + j) * 256 + w * 32 + d], o);
    }
    gbar(bar, ++eb);
    // ---- Wo FULL (redundant per WG; weights L2-shared per XCD) + residual ----
    for (int i = t; i < NJ * 256; i += 512)
      sh[i >> 8][i & 255] = cload(&gq[(b * 5 + (i >> 8)) * 256 + (i & 255)]);
    __syncthreads();
    {
      int c = t & 255, jh = t >> 8;
      const int R0 = (NJ + 1) / 2;
      int jbase = jh ? R0 : 0;
      int nr = jh ? (NJ - R0) : R0;
      int j1 = jbase + (nr > 1 ? 1 : 0), j2 = jbase + (nr > 2 ? 2 : 0);
      float a0 = 0.f, a1 = 0.f, a2 = 0.f;
      const float* wp = Wo + (size_t)l * 65536 + c;
#pragma unroll 4
      for (int k = 0; k < 256; ++k) {
        float wv = wp[(size_t)k * 256];
        a0 = fmaf(sh[jbase][k], wv, a0);
        a1 = fmaf(sh[j1][k], wv, a1);
        a2 = fmaf(sh[j2][k], wv, a2);
      }
      sx[jbase][c] += a0;
      if (nr > 1) sx[jbase + 1][c] += a1;
      if (nr > 2) sx[jbase + 2][c] += a2;
    }
    __syncthreads();
    // ---- LN2 ----
    ln_rows(sx, sh, ln2s + l * 256, ln2b + l * 256, NJ);
    __syncthreads();
    // ---- FF1 slice: cols w*128..w*128+127 of 1024 ----
    for (int job = t; job < 128 * NJ; job += 512) {
      int cl = job & 127, j = job >> 7;
      int col = w * 128 + cl;
      const float* wp = Wff1 + (size_t)l * 262144 + col;
      float acc = 0.f;
#pragma unroll 8
      for (int k = 0; k < 256; ++k) acc = fmaf(sh[j][k], wp[(size_t)k * 1024], acc);
      cstore(&gf1[(b * 5 + j) * 1024 + col], fmaxf(acc + bff1[l * 1024 + col], 0.f));
    }
    gbar(bar, ++eb);
    // ---- FF2 slice: cols w*32, k=1024 (4-way k-split, LDS partials) ----
    for (int i = t; i < NJ * 1024; i += 512)
      f1b[i >> 10][i & 1023] = cload(&gf1[(b * 5 + (i >> 10)) * 1024 + (i & 1023)]);
    __syncthreads();
    for (int job = t; job < NJ * 128; job += 512) {
      int ks = job & 3, cl = (job >> 2) & 31, j = job >> 7;
      int col = w * 32 + cl;
      const float* wp = Wff2 + (size_t)l * 262144 + (size_t)(ks * 256) * 256 + col;
      const float* fp = &f1b[j][ks * 256];
      float acc = 0.f;
#pragma unroll 8
      for (int kk = 0; kk < 256; ++kk) acc = fmaf(fp[kk], wp[(size_t)kk * 256], acc);
      part[job] = acc;
    }
    __syncthreads();
    if (t < NJ * 32) {
      int cl = t & 31, j = t >> 5;
      int col = w * 32 + cl;
      int base = (j * 32 + cl) * 4;
      float s = part[base] + part[base + 1] + part[base + 2] + part[base + 3];
      cstore(&gx[(b * 5 + j) * 256 + col], sx[j][col] + s + bff2[l * 256 + col]);
    }
    gbar(bar, ++eb);
    for (int i = t; i < NJ * 256; i += 512)
      sx[i >> 8][i & 255] = cload(&gx[(b * 5 + (i >> 8)) * 256 + (i & 255)]);
    __syncthreads();
  }
}

// ---------------- persistent decode kernel ----------------
__global__ __launch_bounds__(512, 1) void k_dec(
    const float* __restrict__ codes, const float* __restrict__ tok_emb,
    const float* __restrict__ pos_emb, const float* __restrict__ Wqkv,
    const float* __restrict__ Wo, const float* __restrict__ ln1s,
    const float* __restrict__ ln1b, const float* __restrict__ ln2s,
    const float* __restrict__ ln2b, const float* __restrict__ Wff1,
    const float* __restrict__ bff1, const float* __restrict__ Wff2,
    const float* __restrict__ bff2, const float* __restrict__ hW1,
    const float* __restrict__ hb1, const float* __restrict__ hW2,
    const float* __restrict__ hb2, float* __restrict__ Kc, float* __restrict__ Vc,
    float* __restrict__ gq, float* __restrict__ gf1, float* __restrict__ gx,
    int* __restrict__ bars, float* __restrict__ out) {
  const int t = threadIdx.x;
  const int b = blockIdx.x >> 3;
  const int w = blockIdx.x & 7;
  int* bar = bars + b * 64;
  int eb = 0;

  __shared__ __align__(16) float sx[5][256];
  __shared__ __align__(16) float sh[5][256];
  __shared__ __align__(16) float f1b[5][1024];
  __shared__ float sq[160], sc[200], part[640];
  __shared__ __align__(16) float sLg[5][64];
  __shared__ int sSeq[5][32], sPtr[5][40];
  __shared__ float sLls[5];
  __shared__ float bmF[360];  // bdist 320 | bd 25 | nll 5 | rm 5 | rs 5
  __shared__ int bmI[400];    // osq 160 | opt 200 | bc 25 | nts 5 | oldx 5

  // ---- init replicated per-batch beam state ----
  for (int i = t; i < 160; i += 512) sSeq[i >> 5][i & 31] = ((i & 31) == 0) ? 1 : 0;
  for (int i = t; i < 200; i += 512) sPtr[i / 40][i % 40] = b * 5;  // leader
  if (t < 5) sLls[t] = (t == 0) ? 0.f : -100000.0f;
  __syncthreads();

  for (int ti = 0; ti < 31; ++ti) {
    const bool pre = (ti == 0);
    if (pre) {
      run_chunk<1, 5>(b, w, ti, 0, codes, tok_emb, pos_emb, Wqkv, Wo, ln1s, ln1b, ln2s,
                      ln2b, Wff1, bff1, Wff2, bff2, Kc, Vc, gq, gf1, gx, sx, sh, f1b,
                      sq, sc, part, sSeq, sPtr, bar, eb);
      run_chunk<1, 4>(b, w, ti, 5, codes, tok_emb, pos_emb, Wqkv, Wo, ln1s, ln1b, ln2s,
                      ln2b, Wff1, bff1, Wff2, bff2, Kc, Vc, gq, gf1, gx, sx, sh, f1b,
                      sq, sc, part, sSeq, sPtr, bar, eb);
    } else {
      run_chunk<0, 5>(b, w, ti, 0, codes, tok_emb, pos_emb, Wqkv, Wo, ln1s, ln1b, ln2s,
                      ln2b, Wff1, bff1, Wff2, bff2, Kc, Vc, gq, gf1, gx, sx, sh, f1b,
                      sq, sc, part, sSeq, sPtr, bar, eb);
    }
    // ---- head (FULL, redundant per WG; weights L2-shared per XCD) ----
    {
      const int NJH = pre ? 1 : 5;
      for (int job = t; job < 256 * NJH; job += 512) {
        int c = job & 255, j = job >> 8;
        int src = pre ? 3 : j;  // prefill chunk2: row 8 = local j 3
        const float* wp = hW1 + c;
        float acc = 0.f;
#pragma unroll 8
        for (int k = 0; k < 256; ++k) acc = fmaf(sx[src][k], wp[(size_t)k * 256], acc);
        f1b[j][c] = fmaxf(acc + hb1[c], 0.f);
      }
      __syncthreads();
      for (int job = t; job < 64 * NJH; job += 512) {
        int c = job & 63, j = job >> 6;
        const float* wp = hW2 + c;
        float acc = 0.f;
#pragma unroll 8
        for (int k = 0; k < 256; ++k) acc = fmaf(f1b[j][k], wp[(size_t)k * 64], acc);
        sLg[j][c] = acc + hb2[c];
      }
      __syncthreads();
      if (pre) {
        for (int i = t; i < 320; i += 512) {
          int j = i >> 6, c = i & 63;
          if (j > 0) sLg[j][c] = sLg[0][c];
        }
        __syncthreads();
      }
    }
    // ---- beam update (replicated per WG, exact tie semantics) ----
    {
      float* bdist = bmF;       // 320
      float* bd = bmF + 320;    // 25
      float* nll = bmF + 345;   // 5
      float* rm = bmF + 350;    // 5
      float* rs = bmF + 355;    // 5
      int* osq = bmI;           // 160
      int* opt = bmI + 160;     // 200
      int* bc = bmI + 360;      // 25
      int* nts = bmI + 385;     // 5
      int* oldx = bmI + 390;    // 5
      for (int i = t; i < 160; i += 512) osq[i] = sSeq[i >> 5][i & 31];
      for (int i = t; i < 200; i += 512) opt[i] = sPtr[i / 40][i % 40];
      __syncthreads();
      if (t < 5) {
        float m = -3.4e38f;
        for (int j = 0; j < 64; ++j) m = fmaxf(m, sLg[t][j]);
        float s = 0.f;
        for (int j = 0; j < 64; ++j) s += expf(sLg[t][j] - m);
        rm[t] = m;
        rs[t] = s;
      }
      __syncthreads();
      for (int i = t; i < 320; i += 512) {
        int r = i >> 6;
        bdist[i] = logf(expf(sLg[r][i & 63] - rm[r]) / rs[r] + 1e-8f);
      }
      __syncthreads();
      if (t < 5) {
        float pv = 3.4e38f;
        int pi = -1;
        for (int r = 0; r < 5; ++r) {
          float bv = -3.4e38f;
          int bi = -1;
          for (int j = 0; j < 64; ++j) {
            float v = bdist[t * 64 + j];
            bool lessprev = (v < pv) || (v == pv && j > pi);
            if (lessprev && v > bv) { bv = v; bi = j; }
          }
          bd[t * 5 + r] = bv;
          bc[t * 5 + r] = bi;
          pv = bv;
          pi = bi;
        }
      }
      __syncthreads();
      if (t == 0) {
        float pv = 3.4e38f;
        int pi = -1;
        for (int r = 0; r < 5; ++r) {
          float bv = -3.4e38f;
          int bi = -1;
          for (int idx = 0; idx < 25; ++idx) {
            int kb = idx / 5, jj = idx % 5;
            float v = bd[kb * 5 + jj] + sLls[kb];
            bool lessprev = (v < pv) || (v == pv && idx > pi);
            if (lessprev && v > bv) { bv = v; bi = idx; }
          }
          int kb = bi / 5, jj = bi % 5;
          int tok = bc[kb * 5 + jj];
          nts[r] = tok;
          oldx[r] = kb;
          nll[r] = (tok == 2) ? (bv - 100000.0f) : bv;
          pv = bv;
          pi = bi;
        }
      }
      __syncthreads();
      for (int i = t; i < 160; i += 512) {
        int bm = i >> 5, j2 = i & 31;
        int v = osq[oldx[bm] * 32 + j2];
        if (j2 == ti + 1) v = nts[bm];
        sSeq[bm][j2] = v;
      }
      int r1 = 8 + ti;
      for (int i = t; i < 200; i += 512) {
        int bm = i / 40, j2 = i % 40;
        sPtr[bm][j2] = (j2 <= r1) ? opt[oldx[bm] * 40 + j2] : (b * 5 + bm);
      }
      if (t < 5) sLls[t] = nll[t];
      __syncthreads();
    }
  }
  // ---- output: bseqs (40,32) as float, then blls (40,) ----
  if (w == 0) {
    for (int i = t; i < 160; i += 512) out[b * 160 + i] = (float)sSeq[i >> 5][i & 31];
    if (t < 5) out[1280 + b * 5 + t] = sLls[t];
  }
}

// ---------------- host ----------------
extern "C" void kernel_launch(void* const* d_in, const int* in_sizes, int n_in,
                              void* d_out, int out_size, void* d_ws, size_t ws_size,
                              hipStream_t stream) {
  const float* voxels = (const float*)d_in[0];
  const float* ck1 = (const float*)d_in[1];
  const float* cb1 = (const float*)d_in[2];
  const float* ck2 = (const float*)d_in[3];
  const float* cb2 = (const float*)d_in[4];
  const float* ck3 = (const float*)d_in[5];
  const float* cb3 = (const float*)d_in[6];
  const float* ck4 = (const float*)d_in[7];
  const float* cb4 = (const float*)d_in[8];
  const float* ck5 = (const float*)d_in[9];
  const float* cb5 = (const float*)d_in[10];
  const float* tok_emb = (const float*)d_in[11];
  const float* pos_emb = (const float*)d_in[12];
  const float* Wqkv = (const float*)d_in[13];
  const float* Wo = (const float*)d_in[14];
  const float* ln1s = (const float*)d_in[15];
  const float* ln1b = (const float*)d_in[16];
  const float* ln2s = (const float*)d_in[17];
  const float* ln2b = (const float*)d_in[18];
  const float* Wff1 = (const float*)d_in[19];
  const float* bff1 = (const float*)d_in[20];
  const float* Wff2 = (const float*)d_in[21];
  const float* bff2 = (const float*)d_in[22];
  const float* hW1 = (const float*)d_in[23];
  const float* hb1 = (const float*)d_in[24];
  const float* hW2 = (const float*)d_in[25];
  const float* hb2 = (const float*)d_in[26];

  float* ws = (float*)d_ws;
  // conv chain buffers
  float* c1 = ws;              // 8,388,608 f
  float* c2 = c1 + 8388608;    // 2,097,152 f
  float* c3 = c2 + 2097152;    //   524,288 f
  float* c4 = c3 + 524288;     //   131,072 f
  float* codes = c4 + 131072;  //    16,384 f  (end: 11,157,504)
  // K/V caches alias c1 (dead after conv_t2); per-dispatch acquire invalidates
  // stale conv lines at k_dec start, so normal cached K/V reads are safe.
  float* Kc = ws;            // 1,638,400 f
  float* Vc = Kc + 1638400;  // 1,638,400 f
  // cross-WG buffers + barriers: fresh region past codes (never conv-aliased)
  float* gq = codes + 16384;         // 10,240 f  [8][5][256]
  float* gf1 = gq + 10240;           // 40,960 f  [8][5][1024]
  float* gx = gf1 + 40960;           // 10,240 f  [8][5][256]
  int* bars = (int*)(gx + 10240);    // 512 i     [8][64]

  conv_v1<1, 32, 32, 128><<<8 * 32 * 128, 256, 0, stream>>>(voxels, ck1, cb1, c1);
  conv_t2<<<8 * 16 * 8, 256, 0, stream>>>(c1, ck2, cb2, c2);
  conv_t3<<<8 * 2 * 32, 256, 0, stream>>>(c2, ck3, cb3, c3);
  conv_v2<<<8 * 256, 64, 0, stream>>>(c3, ck4, cb4, c4);
  conv_v3<<<8 * 8, 256, 0, stream>>>(c4, ck5, cb5, codes);

  hipMemsetAsync(bars, 0, 512 * sizeof(int), stream);
  k_dec<<<64, 512, 0, stream>>>(codes, tok_emb, pos_emb, Wqkv, Wo, ln1s, ln1b, ln2s,
                                ln2b, Wff1, bff1, Wff2, bff2, hW1, hb1, hW2, hb2, Kc,
                                Vc, gq, gf1, gx, bars, (float*)d_out);
}

// Round 12
// 12941.554 us; speedup vs baseline: 1.5773x; 1.5582x over previous
//
#include <hip/hip_runtime.h>
#include <math.h>

// ---------------- model constants ----------------
// HD=256 NL=4 NH=8 DH=32 MS=32 MP=8 T=40 ES=64 BATCH=8 BEAMS=5 BB=40
// START=1 END=2 MIN_LL_PEN=-100000
// Decode: 8 groups (batch) x 8 WGs x 512 thr. Column-sliced GEMMs, cross-WG
// data via relaxed agent-scope atomics, fence-free monotonic barrier.
// ROUND 12: fix conv_t2v ic-stride bug (1024 -> 32768). Everything else
// identical to round 11 for clean attribution.

// ---------------- conv1 (unchanged) ----------------
template <int IC, int OC, int OD, int CHUNKS>
__global__ __launch_bounds__(256) void conv_v1(const float* __restrict__ in,
                                               const float* __restrict__ w,
                                               const float* __restrict__ bias,
                                               float* __restrict__ out) {
  constexpr int ID = OD * 2;
  constexpr int ID2 = ID * ID;
  __shared__ float wl[IC * 64];
  int bi = blockIdx.x;
  int chunk = bi % CHUNKS;
  int oc = (bi / CHUNKS) % OC;
  int b = bi / (CHUNKS * OC);
  for (int i = threadIdx.x; i < IC * 64; i += 256) wl[i] = w[oc * IC * 64 + i];
  __syncthreads();
  int s = chunk * 256 + threadIdx.x;
  if (s >= OD * OD * OD) return;
  int od = s / (OD * OD), oh = (s / OD) % OD, ow = s % OD;
  float acc = 0.f;
  for (int ic = 0; ic < IC; ++ic) {
    const float* ipb = in + (size_t)(b * IC + ic) * (ID * ID2);
    const float* wp = wl + ic * 64;
#pragma unroll
    for (int kd = 0; kd < 4; ++kd) {
      int id = od * 2 - 1 + kd;
      if ((unsigned)id < (unsigned)ID) {
#pragma unroll
        for (int kh = 0; kh < 4; ++kh) {
          int ih = oh * 2 - 1 + kh;
          if ((unsigned)ih < (unsigned)ID) {
            const float* rowp = ipb + id * ID2 + ih * ID;
#pragma unroll
            for (int kw = 0; kw < 4; ++kw) {
              int iw = ow * 2 - 1 + kw;
              if ((unsigned)iw < (unsigned)ID)
                acc = fmaf(rowp[iw], wp[kd * 16 + kh * 4 + kw], acc);
            }
          }
        }
      }
    }
  }
  acc += bias[oc];
  out[((size_t)(b * OC + oc) * OD + od) * (OD * OD) + oh * OD + ow] = fmaxf(acc, 0.f);
}

// ---------------- conv2: padded-patch, float4 staging, low-VGPR ----------------
// IC=32 OC=64 ID=32 OD=16. grid = b(8) x ocg(8) x od(16) = 1024; 256 thr (oh,ow).
// patch[4][34][36] zeroed once (pads persist); per-ic stage interior rows via
// float4; weights 8oc x 64taps as float4 rows. OCG=8, acc[8].
__global__ __launch_bounds__(256) void conv_t2v(const float* __restrict__ in,
                                                const float* __restrict__ w,
                                                const float* __restrict__ bias,
                                                float* __restrict__ out) {
  __shared__ float patch[4896];  // [4][34][36]
  __shared__ float wl[512];      // [8][64]
  const int bi = blockIdx.x;
  const int od = bi & 15;
  const int ocg = (bi >> 4) & 7;
  const int b = bi >> 7;
  const int t = threadIdx.x;
  const int oh = t >> 4, ow = t & 15;
  for (int i = t; i < 4896; i += 256) patch[i] = 0.f;

  // row staging: t<136 -> (kd, ihp)
  const int rkd = t / 34, rihp = t - rkd * 34;
  const int rid = od * 2 - 1 + rkd;
  const int rih = rihp - 1;
  const bool rvalid = (t < 136) && ((unsigned)rid < 32u) && ((unsigned)rih < 32u);
  const float* rsrc0 =
      rvalid ? (in + ((size_t)(b * 32) * 32 + rid) * 1024 + rih * 32) : in;
  float* rdst = patch + rkd * 1224 + rihp * 36 + 1;
  const int u = t - 136;  // weight stagers: 120 threads, 128 float4 jobs

  float acc[8];
#pragma unroll
  for (int o = 0; o < 8; ++o) acc[o] = 0.f;
  __syncthreads();

  for (int ic = 0; ic < 32; ++ic) {
    if (rvalid) {
      const float* rs = rsrc0 + (size_t)ic * 32768;  // ic stride = 32*32*32
#pragma unroll
      for (int q = 0; q < 8; ++q) {
        float4 v = *(const float4*)(rs + q * 4);
        rdst[q * 4 + 0] = v.x;
        rdst[q * 4 + 1] = v.y;
        rdst[q * 4 + 2] = v.z;
        rdst[q * 4 + 3] = v.w;
      }
    } else if (u >= 0) {
      {
        int oc_l = u >> 4, grp = u & 15;
        *(float4*)&wl[oc_l * 64 + grp * 4] = *(const float4*)(
            w + (((size_t)(ocg * 8 + oc_l) * 32 + ic) * 64) + grp * 4);
      }
      if (u < 8) {
        int f2 = u + 120;
        int oc_l = f2 >> 4, grp = f2 & 15;
        *(float4*)&wl[oc_l * 64 + grp * 4] = *(const float4*)(
            w + (((size_t)(ocg * 8 + oc_l) * 32 + ic) * 64) + grp * 4);
      }
    }
    __syncthreads();
    const float* pb = patch + (oh * 2) * 36 + ow * 2;
#pragma unroll
    for (int kd = 0; kd < 4; ++kd) {
#pragma unroll
      for (int kh = 0; kh < 4; ++kh) {
        const float* prow = pb + kd * 1224 + kh * 36;
        float p0 = prow[0], p1 = prow[1], p2 = prow[2], p3 = prow[3];
        int tb = kd * 16 + kh * 4;
#pragma unroll
        for (int o = 0; o < 8; ++o) {
          float4 w4 = *(const float4*)&wl[o * 64 + tb];
          acc[o] =
              fmaf(p0, w4.x, fmaf(p1, w4.y, fmaf(p2, w4.z, fmaf(p3, w4.w, acc[o]))));
        }
      }
    }
    __syncthreads();
  }
#pragma unroll
  for (int o = 0; o < 8; ++o) {
    int oc = ocg * 8 + o;
    out[(((size_t)(b * 64 + oc) * 16 + od) * 16 + oh) * 16 + ow] =
        fmaxf(acc[o] + bias[oc], 0.f);
  }
}

// ---------------- conv3: same scheme ----------------
// IC=64 OC=128 ID=16 OD=8. grid = b(8) x odg(2) x ocg(16) = 256; 256 thr
// (od_l 4 x oh 8 x ow 8). patch[10][18][20]; weights 8oc x 64.
__global__ __launch_bounds__(256) void conv_t3v(const float* __restrict__ in,
                                                const float* __restrict__ w,
                                                const float* __restrict__ bias,
                                                float* __restrict__ out) {
  __shared__ float patch[3600];  // [10][18][20]
  __shared__ float wl[512];
  const int bi = blockIdx.x;
  const int ocg = bi & 15;
  const int odg = (bi >> 4) & 1;
  const int b = bi >> 5;
  const int t = threadIdx.x;
  const int od_l = t >> 6;
  const int oh = (t >> 3) & 7, ow = t & 7;
  for (int i = t; i < 3600; i += 256) patch[i] = 0.f;

  const int rp = t / 18, rihp = t - rp * 18;  // t<180
  const int rid = odg * 8 - 1 + rp;
  const int rih = rihp - 1;
  const bool rvalid = (t < 180) && ((unsigned)rid < 16u) && ((unsigned)rih < 16u);
  const float* rsrc0 =
      rvalid ? (in + ((size_t)(b * 64) * 16 + rid) * 256 + rih * 16) : in;
  float* rdst = patch + rp * 360 + rihp * 20 + 1;
  const int u = t - 180;  // 76 threads, 128 float4 jobs

  float acc[8];
#pragma unroll
  for (int o = 0; o < 8; ++o) acc[o] = 0.f;
  __syncthreads();

  for (int ic = 0; ic < 64; ++ic) {
    if (rvalid) {
      const float* rs = rsrc0 + (size_t)ic * 4096;  // ic stride = 16*16*16
#pragma unroll
      for (int q = 0; q < 4; ++q) {
        float4 v = *(const float4*)(rs + q * 4);
        rdst[q * 4 + 0] = v.x;
        rdst[q * 4 + 1] = v.y;
        rdst[q * 4 + 2] = v.z;
        rdst[q * 4 + 3] = v.w;
      }
    } else if (u >= 0) {
      {
        int oc_l = u >> 4, grp = u & 15;
        *(float4*)&wl[oc_l * 64 + grp * 4] = *(const float4*)(
            w + (((size_t)(ocg * 8 + oc_l) * 64 + ic) * 64) + grp * 4);
      }
      if (u < 52) {
        int f2 = u + 76;
        int oc_l = f2 >> 4, grp = f2 & 15;
        *(float4*)&wl[oc_l * 64 + grp * 4] = *(const float4*)(
            w + (((size_t)(ocg * 8 + oc_l) * 64 + ic) * 64) + grp * 4);
      }
    }
    __syncthreads();
    const float* pb = patch + (od_l * 2) * 360 + (oh * 2) * 20 + ow * 2;
#pragma unroll
    for (int kd = 0; kd < 4; ++kd) {
#pragma unroll
      for (int kh = 0; kh < 4; ++kh) {
        const float* prow = pb + kd * 360 + kh * 20;
        float p0 = prow[0], p1 = prow[1], p2 = prow[2], p3 = prow[3];
        int tb = kd * 16 + kh * 4;
#pragma unroll
        for (int o = 0; o < 8; ++o) {
          float4 w4 = *(const float4*)&wl[o * 64 + tb];
          acc[o] =
              fmaf(p0, w4.x, fmaf(p1, w4.y, fmaf(p2, w4.z, fmaf(p3, w4.w, acc[o]))));
        }
      }
    }
    __syncthreads();
  }
  const int od = odg * 4 + od_l;
#pragma unroll
  for (int o = 0; o < 8; ++o) {
    int oc = ocg * 8 + o;
    out[(((size_t)(b * 128 + oc) * 8 + od) * 8 + oh) * 8 + ow] =
        fmaxf(acc[o] + bias[oc], 0.f);
  }
}

// ---------------- conv4 (unchanged) ----------------
__global__ __launch_bounds__(64) void conv_v2(const float* __restrict__ in,
                                              const float* __restrict__ w,
                                              const float* __restrict__ bias,
                                              float* __restrict__ out) {
  constexpr int IC = 128, OD = 4, ID = 8, ID2 = 64;
  __shared__ float wl[IC * 64];
  int oc = blockIdx.x % 256;
  int b = blockIdx.x / 256;
  for (int i = threadIdx.x; i < IC * 64; i += 64) wl[i] = w[oc * IC * 64 + i];
  __syncthreads();
  int s = threadIdx.x;
  int od = s >> 4, oh = (s >> 2) & 3, ow = s & 3;
  float acc = 0.f;
  for (int ic = 0; ic < IC; ++ic) {
    const float* ipb = in + (size_t)(b * IC + ic) * (ID * ID2);
    const float* wp = wl + ic * 64;
#pragma unroll
    for (int kd = 0; kd < 4; ++kd) {
      int id = od * 2 - 1 + kd;
      if ((unsigned)id < (unsigned)ID) {
#pragma unroll
        for (int kh = 0; kh < 4; ++kh) {
          int ih = oh * 2 - 1 + kh;
          if ((unsigned)ih < (unsigned)ID) {
            const float* rowp = ipb + id * ID2 + ih * ID;
#pragma unroll
            for (int kw = 0; kw < 4; ++kw) {
              int iw = ow * 2 - 1 + kw;
              if ((unsigned)iw < (unsigned)ID)
                acc = fmaf(rowp[iw], wp[kd * 16 + kh * 4 + kw], acc);
            }
          }
        }
      }
    }
  }
  acc += bias[oc];
  out[((size_t)(b * 256 + oc) * OD + od) * 16 + oh * 4 + ow] = fmaxf(acc, 0.f);
}

// ---------------- conv5: 256 blocks, 4-way k-split ----------------
__global__ __launch_bounds__(256) void conv_v3v(const float* __restrict__ in,
                                                const float* __restrict__ w,
                                                const float* __restrict__ bias,
                                                float* __restrict__ codes) {
  __shared__ float inl[16384];  // 64KB
  __shared__ float part[256];
  const int ocg = blockIdx.x & 31;
  const int b = blockIdx.x >> 5;
  const int t = threadIdx.x;
  for (int i = t; i < 4096; i += 256)
    *(float4*)&inl[i * 4] = *(const float4*)(in + (size_t)b * 16384 + i * 4);
  __syncthreads();
  const int ks = t >> 6, s = (t >> 3) & 7, oc_l = t & 7;
  const int oc = ocg * 8 + oc_l;
  const int od = s >> 2, oh = (s >> 1) & 1, ow = s & 1;
  float acc = 0.f;
  const float* wb0 = w + ((size_t)oc * 256 + ks * 64) * 64;
  const float* ib0 = inl + ks * 64 * 64;
  for (int ic = 0; ic < 64; ++ic) {
    const float* ib = ib0 + ic * 64;
    const float* wb = wb0 + ic * 64;
#pragma unroll
    for (int kd = 0; kd < 4; ++kd) {
      int id = od * 2 - 1 + kd;
      if ((unsigned)id < 4u) {
#pragma unroll
        for (int kh = 0; kh < 4; ++kh) {
          int ih = oh * 2 - 1 + kh;
          if ((unsigned)ih < 4u) {
#pragma unroll
            for (int kw = 0; kw < 4; ++kw) {
              int iw = ow * 2 - 1 + kw;
              if ((unsigned)iw < 4u)
                acc = fmaf(ib[id * 16 + ih * 4 + iw], wb[kd * 16 + kh * 4 + kw], acc);
            }
          }
        }
      }
    }
  }
  part[t] = acc;
  __syncthreads();
  if (t < 64) {
    float sv = part[t] + part[t + 64] + part[t + 128] + part[t + 192];
    int s2 = t >> 3, oc2 = ocg * 8 + (t & 7);
    codes[(b * 8 + s2) * 256 + oc2] = fmaxf(sv + bias[oc2], 0.f);
  }
}

// ---------------- coherent access helpers (relaxed, agent scope) ----------------
__device__ __forceinline__ float cload(const float* p) {
  return __hip_atomic_load(p, __ATOMIC_RELAXED, __HIP_MEMORY_SCOPE_AGENT);
}
__device__ __forceinline__ void cstore(float* p, float v) {
  __hip_atomic_store(p, v, __ATOMIC_RELAXED, __HIP_MEMORY_SCOPE_AGENT);
}

// ---------------- fence-free 8-WG barrier (monotonic count + flag) ----------------
__device__ __forceinline__ void gbar(int* bar, int e) {
  __syncthreads();
  if (threadIdx.x == 0) {
    int prev =
        __hip_atomic_fetch_add(&bar[0], 1, __ATOMIC_RELAXED, __HIP_MEMORY_SCOPE_AGENT);
    if (prev == 8 * e - 1) {
      __hip_atomic_store(&bar[32], e, __ATOMIC_RELAXED, __HIP_MEMORY_SCOPE_AGENT);
    } else {
      while (__hip_atomic_load(&bar[32], __ATOMIC_RELAXED, __HIP_MEMORY_SCOPE_AGENT) < e)
        __builtin_amdgcn_s_sleep(1);
    }
  }
  __syncthreads();
}

// ---------------- LayerNorm: one wave per row ----------------
__device__ __forceinline__ void ln_rows(const float (*sxx)[256], float (*shh)[256],
                                        const float* __restrict__ gsc,
                                        const float* __restrict__ gbi, int NJ) {
  int wv = threadIdx.x >> 6, lane = threadIdx.x & 63;
  if (wv < NJ) {
    float4 xv = *(const float4*)&sxx[wv][lane * 4];
    float s = xv.x + xv.y + xv.z + xv.w;
#pragma unroll
    for (int off = 32; off >= 1; off >>= 1) s += __shfl_xor(s, off);
    float mean = s * (1.f / 256.f);
    float d0 = xv.x - mean, d1 = xv.y - mean, d2 = xv.z - mean, d3 = xv.w - mean;
    float v = d0 * d0 + d1 * d1 + d2 * d2 + d3 * d3;
#pragma unroll
    for (int off = 32; off >= 1; off >>= 1) v += __shfl_xor(v, off);
    float rsd = 1.f / sqrtf(v * (1.f / 256.f) + 1e-5f);
    float4 s4 = *(const float4*)&gsc[lane * 4];
    float4 b4 = *(const float4*)&gbi[lane * 4];
    float4 hv;
    hv.x = d0 * rsd * s4.x + b4.x;
    hv.y = d1 * rsd * s4.y + b4.y;
    hv.z = d2 * rsd * s4.z + b4.z;
    hv.w = d3 * rsd * s4.w + b4.w;
    *(float4*)&shh[wv][lane * 4] = hv;
  }
}

// ---------------- per-chunk transformer layers (UNCHANGED) ----------------
template <int PRE, int NJ>
__device__ void run_chunk(int b, int w, int ti, int rbase,
                          const float* __restrict__ codes,
                          const float* __restrict__ tok_emb,
                          const float* __restrict__ pos_emb,
                          const float* __restrict__ Wqkv, const float* __restrict__ Wo,
                          const float* __restrict__ ln1s, const float* __restrict__ ln1b,
                          const float* __restrict__ ln2s, const float* __restrict__ ln2b,
                          const float* __restrict__ Wff1, const float* __restrict__ bff1,
                          const float* __restrict__ Wff2, const float* __restrict__ bff2,
                          float* __restrict__ Kc, float* __restrict__ Vc,
                          float* __restrict__ gq, float* __restrict__ gf1,
                          float* __restrict__ gx, float (*sx)[256], float (*sh)[256],
                          float (*f1b)[1024], float* sq, float* sc, float* part,
                          const int (*sSeq)[32], const int (*sPtr)[40], int* bar,
                          int& eb) {
  const int t = threadIdx.x;
  for (int i = t; i < NJ * 256; i += 512) {
    int j = i >> 8, c = i & 255;
    int row = PRE ? (rbase + j) : (8 + ti);
    float v;
    if (PRE)
      v = (row < 8) ? codes[(b * 8 + row) * 256 + c] : tok_emb[256 + c];  // START=1
    else
      v = tok_emb[sSeq[j][ti] * 256 + c];
    sx[j][c] = v + pos_emb[row * 256 + c];
  }
  __syncthreads();

  for (int l = 0; l < 4; ++l) {
    ln_rows(sx, sh, ln1s + l * 256, ln1b + l * 256, NJ);
    __syncthreads();
    if (t < 96 * NJ) {
      int cl = t % 96, j = t / 96;
      int col = w * 96 + cl;
      const float* wp = Wqkv + (size_t)l * 196608 + col;
      float acc = 0.f;
#pragma unroll 8
      for (int k = 0; k < 256; ++k) acc = fmaf(sh[j][k], wp[(size_t)k * 768], acc);
      int row = PRE ? (rbase + j) : (8 + ti);
      int slot = PRE ? (b * 5) : (b * 5 + j);
      if (col < 256)
        cstore(&gq[(b * 5 + j) * 256 + col], acc);
      else if (col < 512)
        cstore(&Kc[((size_t)(l * 40 + slot) * 40 + row) * 256 + col - 256], acc);
      else
        cstore(&Vc[((size_t)(l * 40 + slot) * 40 + row) * 256 + col - 512], acc);
    }
    gbar(bar, ++eb);
    if (t < NJ * 32) sq[t] = cload(&gq[(b * 5 + (t >> 5)) * 256 + w * 32 + (t & 31)]);
    __syncthreads();
    if (t < NJ * 40) {
      int j = t / 40, jj = t - j * 40;
      int rowj = PRE ? (rbase + j) : (8 + ti);
      if (jj <= rowj) {
        const float* kp = Kc + ((size_t)(l * 40 + sPtr[j][jj]) * 40 + jj) * 256 + w * 32;
        float s = 0.f;
#pragma unroll
        for (int d = 0; d < 32; d += 4) {
          float4 k4 = *(const float4*)(kp + d);
          s = fmaf(sq[j * 32 + d], k4.x,
                   fmaf(sq[j * 32 + d + 1], k4.y,
                        fmaf(sq[j * 32 + d + 2], k4.z,
                             fmaf(sq[j * 32 + d + 3], k4.w, s))));
        }
        sc[j * 40 + jj] = s * 0.17677669529663687f;  // 1/sqrt(32)
      }
    }
    __syncthreads();
    if (t < NJ) {
      int rowj = PRE ? (rbase + t) : (8 + ti);
      float m = -3.4e38f;
      for (int jj = 0; jj <= rowj; ++jj) m = fmaxf(m, sc[t * 40 + jj]);
      float su = 0.f;
      for (int jj = 0; jj <= rowj; ++jj) su += expf(sc[t * 40 + jj] - m);
      for (int jj = 0; jj <= rowj; ++jj) sc[t * 40 + jj] = expf(sc[t * 40 + jj] - m) / su;
    }
    __syncthreads();
    if (t < NJ * 32) {
      int j = t >> 5, d = t & 31;
      int rowj = PRE ? (rbase + j) : (8 + ti);
      float o = 0.f;
      for (int jj = 0; jj <= rowj; ++jj)
        o = fmaf(sc[j * 40 + jj],
                 Vc[((size_t)(l * 40 + sPtr[j][jj]) * 40 + jj) * 256 + w * 32 + d], o);
      cstore(&gq[(b * 5 + j) * 256 + w * 32 + d], o);
    }
    gbar(bar, ++eb);
    for (int i = t; i < NJ * 256; i += 512)
      sh[i >> 8][i & 255] = cload(&gq[(b * 5 + (i >> 8)) * 256 + (i & 255)]);
    __syncthreads();
    {
      int c = t & 255, jh = t >> 8;
      const int R0 = (NJ + 1) / 2;
      int jbase = jh ? R0 : 0;
      int nr = jh ? (NJ - R0) : R0;
      int j1 = jbase + (nr > 1 ? 1 : 0), j2 = jbase + (nr > 2 ? 2 : 0);
      float a0 = 0.f, a1 = 0.f, a2 = 0.f;
      const float* wp = Wo + (size_t)l * 65536 + c;
#pragma unroll 4
      for (int k = 0; k < 256; ++k) {
        float wv = wp[(size_t)k * 256];
        a0 = fmaf(sh[jbase][k], wv, a0);
        a1 = fmaf(sh[j1][k], wv, a1);
        a2 = fmaf(sh[j2][k], wv, a2);
      }
      sx[jbase][c] += a0;
      if (nr > 1) sx[jbase + 1][c] += a1;
      if (nr > 2) sx[jbase + 2][c] += a2;
    }
    __syncthreads();
    ln_rows(sx, sh, ln2s + l * 256, ln2b + l * 256, NJ);
    __syncthreads();
    for (int job = t; job < 128 * NJ; job += 512) {
      int cl = job & 127, j = job >> 7;
      int col = w * 128 + cl;
      const float* wp = Wff1 + (size_t)l * 262144 + col;
      float acc = 0.f;
#pragma unroll 8
      for (int k = 0; k < 256; ++k) acc = fmaf(sh[j][k], wp[(size_t)k * 1024], acc);
      cstore(&gf1[(b * 5 + j) * 1024 + col], fmaxf(acc + bff1[l * 1024 + col], 0.f));
    }
    gbar(bar, ++eb);
    for (int i = t; i < NJ * 1024; i += 512)
      f1b[i >> 10][i & 1023] = cload(&gf1[(b * 5 + (i >> 10)) * 1024 + (i & 1023)]);
    __syncthreads();
    for (int job = t; job < NJ * 128; job += 512) {
      int ks = job & 3, cl = (job >> 2) & 31, j = job >> 7;
      int col = w * 32 + cl;
      const float* wp = Wff2 + (size_t)l * 262144 + (size_t)(ks * 256) * 256 + col;
      const float* fp = &f1b[j][ks * 256];
      float acc = 0.f;
#pragma unroll 8
      for (int kk = 0; kk < 256; ++kk) acc = fmaf(fp[kk], wp[(size_t)kk * 256], acc);
      part[job] = acc;
    }
    __syncthreads();
    if (t < NJ * 32) {
      int cl = t & 31, j = t >> 5;
      int col = w * 32 + cl;
      int base = (j * 32 + cl) * 4;
      float s = part[base] + part[base + 1] + part[base + 2] + part[base + 3];
      cstore(&gx[(b * 5 + j) * 256 + col], sx[j][col] + s + bff2[l * 256 + col]);
    }
    gbar(bar, ++eb);
    for (int i = t; i < NJ * 256; i += 512)
      sx[i >> 8][i & 255] = cload(&gx[(b * 5 + (i >> 8)) * 256 + (i & 255)]);
    __syncthreads();
  }
}

// ---------------- persistent decode kernel (UNCHANGED) ----------------
__global__ __launch_bounds__(512, 1) void k_dec(
    const float* __restrict__ codes, const float* __restrict__ tok_emb,
    const float* __restrict__ pos_emb, const float* __restrict__ Wqkv,
    const float* __restrict__ Wo, const float* __restrict__ ln1s,
    const float* __restrict__ ln1b, const float* __restrict__ ln2s,
    const float* __restrict__ ln2b, const float* __restrict__ Wff1,
    const float* __restrict__ bff1, const float* __restrict__ Wff2,
    const float* __restrict__ bff2, const float* __restrict__ hW1,
    const float* __restrict__ hb1, const float* __restrict__ hW2,
    const float* __restrict__ hb2, float* __restrict__ Kc, float* __restrict__ Vc,
    float* __restrict__ gq, float* __restrict__ gf1, float* __restrict__ gx,
    int* __restrict__ bars, float* __restrict__ out) {
  const int t = threadIdx.x;
  const int b = blockIdx.x >> 3;
  const int w = blockIdx.x & 7;
  int* bar = bars + b * 64;
  int eb = 0;

  __shared__ __align__(16) float sx[5][256];
  __shared__ __align__(16) float sh[5][256];
  __shared__ __align__(16) float f1b[5][1024];
  __shared__ float sq[160], sc[200], part[640];
  __shared__ __align__(16) float sLg[5][64];
  __shared__ int sSeq[5][32], sPtr[5][40];
  __shared__ float sLls[5];
  __shared__ float bmF[360];
  __shared__ int bmI[400];

  for (int i = t; i < 160; i += 512) sSeq[i >> 5][i & 31] = ((i & 31) == 0) ? 1 : 0;
  for (int i = t; i < 200; i += 512) sPtr[i / 40][i % 40] = b * 5;
  if (t < 5) sLls[t] = (t == 0) ? 0.f : -100000.0f;
  __syncthreads();

  for (int ti = 0; ti < 31; ++ti) {
    const bool pre = (ti == 0);
    if (pre) {
      run_chunk<1, 5>(b, w, ti, 0, codes, tok_emb, pos_emb, Wqkv, Wo, ln1s, ln1b, ln2s,
                      ln2b, Wff1, bff1, Wff2, bff2, Kc, Vc, gq, gf1, gx, sx, sh, f1b,
                      sq, sc, part, sSeq, sPtr, bar, eb);
      run_chunk<1, 4>(b, w, ti, 5, codes, tok_emb, pos_emb, Wqkv, Wo, ln1s, ln1b, ln2s,
                      ln2b, Wff1, bff1, Wff2, bff2, Kc, Vc, gq, gf1, gx, sx, sh, f1b,
                      sq, sc, part, sSeq, sPtr, bar, eb);
    } else {
      run_chunk<0, 5>(b, w, ti, 0, codes, tok_emb, pos_emb, Wqkv, Wo, ln1s, ln1b, ln2s,
                      ln2b, Wff1, bff1, Wff2, bff2, Kc, Vc, gq, gf1, gx, sx, sh, f1b,
                      sq, sc, part, sSeq, sPtr, bar, eb);
    }
    {
      const int NJH = pre ? 1 : 5;
      for (int job = t; job < 256 * NJH; job += 512) {
        int c = job & 255, j = job >> 8;
        int src = pre ? 3 : j;
        const float* wp = hW1 + c;
        float acc = 0.f;
#pragma unroll 8
        for (int k = 0; k < 256; ++k) acc = fmaf(sx[src][k], wp[(size_t)k * 256], acc);
        f1b[j][c] = fmaxf(acc + hb1[c], 0.f);
      }
      __syncthreads();
      for (int job = t; job < 64 * NJH; job += 512) {
        int c = job & 63, j = job >> 6;
        const float* wp = hW2 + c;
        float acc = 0.f;
#pragma unroll 8
        for (int k = 0; k < 256; ++k) acc = fmaf(f1b[j][k], wp[(size_t)k * 64], acc);
        sLg[j][c] = acc + hb2[c];
      }
      __syncthreads();
      if (pre) {
        for (int i = t; i < 320; i += 512) {
          int j = i >> 6, c = i & 63;
          if (j > 0) sLg[j][c] = sLg[0][c];
        }
        __syncthreads();
      }
    }
    {
      float* bdist = bmF;
      float* bd = bmF + 320;
      float* nll = bmF + 345;
      float* rm = bmF + 350;
      float* rs = bmF + 355;
      int* osq = bmI;
      int* opt = bmI + 160;
      int* bc = bmI + 360;
      int* nts = bmI + 385;
      int* oldx = bmI + 390;
      for (int i = t; i < 160; i += 512) osq[i] = sSeq[i >> 5][i & 31];
      for (int i = t; i < 200; i += 512) opt[i] = sPtr[i / 40][i % 40];
      __syncthreads();
      if (t < 5) {
        float m = -3.4e38f;
        for (int j = 0; j < 64; ++j) m = fmaxf(m, sLg[t][j]);
        float s = 0.f;
        for (int j = 0; j < 64; ++j) s += expf(sLg[t][j] - m);
        rm[t] = m;
        rs[t] = s;
      }
      __syncthreads();
      for (int i = t; i < 320; i += 512) {
        int r = i >> 6;
        bdist[i] = logf(expf(sLg[r][i & 63] - rm[r]) / rs[r] + 1e-8f);
      }
      __syncthreads();
      if (t < 5) {
        float pv = 3.4e38f;
        int pi = -1;
        for (int r = 0; r < 5; ++r) {
          float bv = -3.4e38f;
          int bi = -1;
          for (int j = 0; j < 64; ++j) {
            float v = bdist[t * 64 + j];
            bool lessprev = (v < pv) || (v == pv && j > pi);
            if (lessprev && v > bv) { bv = v; bi = j; }
          }
          bd[t * 5 + r] = bv;
          bc[t * 5 + r] = bi;
          pv = bv;
          pi = bi;
        }
      }
      __syncthreads();
      if (t == 0) {
        float pv = 3.4e38f;
        int pi = -1;
        for (int r = 0; r < 5; ++r) {
          float bv = -3.4e38f;
          int bi = -1;
          for (int idx = 0; idx < 25; ++idx) {
            int kb = idx / 5, jj = idx % 5;
            float v = bd[kb * 5 + jj] + sLls[kb];
            bool lessprev = (v < pv) || (v == pv && idx > pi);
            if (lessprev && v > bv) { bv = v; bi = idx; }
          }
          int kb = bi / 5, jj = bi % 5;
          int tok = bc[kb * 5 + jj];
          nts[r] = tok;
          oldx[r] = kb;
          nll[r] = (tok == 2) ? (bv - 100000.0f) : bv;
          pv = bv;
          pi = bi;
        }
      }
      __syncthreads();
      for (int i = t; i < 160; i += 512) {
        int bm = i >> 5, j2 = i & 31;
        int v = osq[oldx[bm] * 32 + j2];
        if (j2 == ti + 1) v = nts[bm];
        sSeq[bm][j2] = v;
      }
      int r1 = 8 + ti;
      for (int i = t; i < 200; i += 512) {
        int bm = i / 40, j2 = i % 40;
        sPtr[bm][j2] = (j2 <= r1) ? opt[oldx[bm] * 40 + j2] : (b * 5 + bm);
      }
      if (t < 5) sLls[t] = nll[t];
      __syncthreads();
    }
  }
  if (w == 0) {
    for (int i = t; i < 160; i += 512) out[b * 160 + i] = (float)sSeq[i >> 5][i & 31];
    if (t < 5) out[1280 + b * 5 + t] = sLls[t];
  }
}

// ---------------- host ----------------
extern "C" void kernel_launch(void* const* d_in, const int* in_sizes, int n_in,
                              void* d_out, int out_size, void* d_ws, size_t ws_size,
                              hipStream_t stream) {
  const float* voxels = (const float*)d_in[0];
  const float* ck1 = (const float*)d_in[1];
  const float* cb1 = (const float*)d_in[2];
  const float* ck2 = (const float*)d_in[3];
  const float* cb2 = (const float*)d_in[4];
  const float* ck3 = (const float*)d_in[5];
  const float* cb3 = (const float*)d_in[6];
  const float* ck4 = (const float*)d_in[7];
  const float* cb4 = (const float*)d_in[8];
  const float* ck5 = (const float*)d_in[9];
  const float* cb5 = (const float*)d_in[10];
  const float* tok_emb = (const float*)d_in[11];
  const float* pos_emb = (const float*)d_in[12];
  const float* Wqkv = (const float*)d_in[13];
  const float* Wo = (const float*)d_in[14];
  const float* ln1s = (const float*)d_in[15];
  const float* ln1b = (const float*)d_in[16];
  const float* ln2s = (const float*)d_in[17];
  const float* ln2b = (const float*)d_in[18];
  const float* Wff1 = (const float*)d_in[19];
  const float* bff1 = (const float*)d_in[20];
  const float* Wff2 = (const float*)d_in[21];
  const float* bff2 = (const float*)d_in[22];
  const float* hW1 = (const float*)d_in[23];
  const float* hb1 = (const float*)d_in[24];
  const float* hW2 = (const float*)d_in[25];
  const float* hb2 = (const float*)d_in[26];

  float* ws = (float*)d_ws;
  float* c1 = ws;              // 8,388,608 f
  float* c2 = c1 + 8388608;    // 2,097,152 f
  float* c3 = c2 + 2097152;    //   524,288 f
  float* c4 = c3 + 524288;     //   131,072 f
  float* codes = c4 + 131072;  //    16,384 f
  float* Kc = ws;              // 1,638,400 f (aliases c1, dead after conv_t2v)
  float* Vc = Kc + 1638400;    // 1,638,400 f
  float* gq = codes + 16384;   // 10,240 f
  float* gf1 = gq + 10240;     // 40,960 f
  float* gx = gf1 + 40960;     // 10,240 f
  int* bars = (int*)(gx + 10240);  // 512 i

  conv_v1<1, 32, 32, 128><<<8 * 32 * 128, 256, 0, stream>>>(voxels, ck1, cb1, c1);
  conv_t2v<<<1024, 256, 0, stream>>>(c1, ck2, cb2, c2);
  conv_t3v<<<256, 256, 0, stream>>>(c2, ck3, cb3, c3);
  conv_v2<<<8 * 256, 64, 0, stream>>>(c3, ck4, cb4, c4);
  conv_v3v<<<256, 256, 0, stream>>>(c4, ck5, cb5, codes);

  hipMemsetAsync(bars, 0, 512 * sizeof(int), stream);
  k_dec<<<64, 512, 0, stream>>>(codes, tok_emb, pos_emb, Wqkv, Wo, ln1s, ln1b, ln2s,
                                ln2b, Wff1, bff1, Wff2, bff2, hW1, hb1, hW2, hb2, Kc,
                                Vc, gq, gf1, gx, bars, (float*)d_out);
}

// Round 13
// 9592.253 us; speedup vs baseline: 2.1281x; 1.3492x over previous
//
#include <hip/hip_runtime.h>
#include <math.h>

// ---------------- model constants ----------------
// HD=256 NL=4 NH=8 DH=32 MS=32 MP=8 T=40 ES=64 BATCH=8 BEAMS=5 BB=40
// START=1 END=2 MIN_LL_PEN=-100000
// Decode: 8 groups (batch) x 8 WGs x 512 thr.
// ROUND 13: head-sliced QKV/attention (fully WG-local, private K/V slices),
// k-sliced Wo/FF2 with partial-exchange + redundant reduce -> 2 barriers/layer.
// Convs identical to round 12 (proven).

// ---------------- conv1 (unchanged) ----------------
template <int IC, int OC, int OD, int CHUNKS>
__global__ __launch_bounds__(256) void conv_v1(const float* __restrict__ in,
                                               const float* __restrict__ w,
                                               const float* __restrict__ bias,
                                               float* __restrict__ out) {
  constexpr int ID = OD * 2;
  constexpr int ID2 = ID * ID;
  __shared__ float wl[IC * 64];
  int bi = blockIdx.x;
  int chunk = bi % CHUNKS;
  int oc = (bi / CHUNKS) % OC;
  int b = bi / (CHUNKS * OC);
  for (int i = threadIdx.x; i < IC * 64; i += 256) wl[i] = w[oc * IC * 64 + i];
  __syncthreads();
  int s = chunk * 256 + threadIdx.x;
  if (s >= OD * OD * OD) return;
  int od = s / (OD * OD), oh = (s / OD) % OD, ow = s % OD;
  float acc = 0.f;
  for (int ic = 0; ic < IC; ++ic) {
    const float* ipb = in + (size_t)(b * IC + ic) * (ID * ID2);
    const float* wp = wl + ic * 64;
#pragma unroll
    for (int kd = 0; kd < 4; ++kd) {
      int id = od * 2 - 1 + kd;
      if ((unsigned)id < (unsigned)ID) {
#pragma unroll
        for (int kh = 0; kh < 4; ++kh) {
          int ih = oh * 2 - 1 + kh;
          if ((unsigned)ih < (unsigned)ID) {
            const float* rowp = ipb + id * ID2 + ih * ID;
#pragma unroll
            for (int kw = 0; kw < 4; ++kw) {
              int iw = ow * 2 - 1 + kw;
              if ((unsigned)iw < (unsigned)ID)
                acc = fmaf(rowp[iw], wp[kd * 16 + kh * 4 + kw], acc);
            }
          }
        }
      }
    }
  }
  acc += bias[oc];
  out[((size_t)(b * OC + oc) * OD + od) * (OD * OD) + oh * OD + ow] = fmaxf(acc, 0.f);
}

// ---------------- conv2 (round-12, proven) ----------------
__global__ __launch_bounds__(256) void conv_t2v(const float* __restrict__ in,
                                                const float* __restrict__ w,
                                                const float* __restrict__ bias,
                                                float* __restrict__ out) {
  __shared__ float patch[4896];  // [4][34][36]
  __shared__ float wl[512];      // [8][64]
  const int bi = blockIdx.x;
  const int od = bi & 15;
  const int ocg = (bi >> 4) & 7;
  const int b = bi >> 7;
  const int t = threadIdx.x;
  const int oh = t >> 4, ow = t & 15;
  for (int i = t; i < 4896; i += 256) patch[i] = 0.f;

  const int rkd = t / 34, rihp = t - rkd * 34;
  const int rid = od * 2 - 1 + rkd;
  const int rih = rihp - 1;
  const bool rvalid = (t < 136) && ((unsigned)rid < 32u) && ((unsigned)rih < 32u);
  const float* rsrc0 =
      rvalid ? (in + ((size_t)(b * 32) * 32 + rid) * 1024 + rih * 32) : in;
  float* rdst = patch + rkd * 1224 + rihp * 36 + 1;
  const int u = t - 136;

  float acc[8];
#pragma unroll
  for (int o = 0; o < 8; ++o) acc[o] = 0.f;
  __syncthreads();

  for (int ic = 0; ic < 32; ++ic) {
    if (rvalid) {
      const float* rs = rsrc0 + (size_t)ic * 32768;
#pragma unroll
      for (int q = 0; q < 8; ++q) {
        float4 v = *(const float4*)(rs + q * 4);
        rdst[q * 4 + 0] = v.x;
        rdst[q * 4 + 1] = v.y;
        rdst[q * 4 + 2] = v.z;
        rdst[q * 4 + 3] = v.w;
      }
    } else if (u >= 0) {
      {
        int oc_l = u >> 4, grp = u & 15;
        *(float4*)&wl[oc_l * 64 + grp * 4] = *(const float4*)(
            w + (((size_t)(ocg * 8 + oc_l) * 32 + ic) * 64) + grp * 4);
      }
      if (u < 8) {
        int f2 = u + 120;
        int oc_l = f2 >> 4, grp = f2 & 15;
        *(float4*)&wl[oc_l * 64 + grp * 4] = *(const float4*)(
            w + (((size_t)(ocg * 8 + oc_l) * 32 + ic) * 64) + grp * 4);
      }
    }
    __syncthreads();
    const float* pb = patch + (oh * 2) * 36 + ow * 2;
#pragma unroll
    for (int kd = 0; kd < 4; ++kd) {
#pragma unroll
      for (int kh = 0; kh < 4; ++kh) {
        const float* prow = pb + kd * 1224 + kh * 36;
        float p0 = prow[0], p1 = prow[1], p2 = prow[2], p3 = prow[3];
        int tb = kd * 16 + kh * 4;
#pragma unroll
        for (int o = 0; o < 8; ++o) {
          float4 w4 = *(const float4*)&wl[o * 64 + tb];
          acc[o] =
              fmaf(p0, w4.x, fmaf(p1, w4.y, fmaf(p2, w4.z, fmaf(p3, w4.w, acc[o]))));
        }
      }
    }
    __syncthreads();
  }
#pragma unroll
  for (int o = 0; o < 8; ++o) {
    int oc = ocg * 8 + o;
    out[(((size_t)(b * 64 + oc) * 16 + od) * 16 + oh) * 16 + ow] =
        fmaxf(acc[o] + bias[oc], 0.f);
  }
}

// ---------------- conv3 (round-12, proven) ----------------
__global__ __launch_bounds__(256) void conv_t3v(const float* __restrict__ in,
                                                const float* __restrict__ w,
                                                const float* __restrict__ bias,
                                                float* __restrict__ out) {
  __shared__ float patch[3600];  // [10][18][20]
  __shared__ float wl[512];
  const int bi = blockIdx.x;
  const int ocg = bi & 15;
  const int odg = (bi >> 4) & 1;
  const int b = bi >> 5;
  const int t = threadIdx.x;
  const int od_l = t >> 6;
  const int oh = (t >> 3) & 7, ow = t & 7;
  for (int i = t; i < 3600; i += 256) patch[i] = 0.f;

  const int rp = t / 18, rihp = t - rp * 18;
  const int rid = odg * 8 - 1 + rp;
  const int rih = rihp - 1;
  const bool rvalid = (t < 180) && ((unsigned)rid < 16u) && ((unsigned)rih < 16u);
  const float* rsrc0 =
      rvalid ? (in + ((size_t)(b * 64) * 16 + rid) * 256 + rih * 16) : in;
  float* rdst = patch + rp * 360 + rihp * 20 + 1;
  const int u = t - 180;

  float acc[8];
#pragma unroll
  for (int o = 0; o < 8; ++o) acc[o] = 0.f;
  __syncthreads();

  for (int ic = 0; ic < 64; ++ic) {
    if (rvalid) {
      const float* rs = rsrc0 + (size_t)ic * 4096;
#pragma unroll
      for (int q = 0; q < 4; ++q) {
        float4 v = *(const float4*)(rs + q * 4);
        rdst[q * 4 + 0] = v.x;
        rdst[q * 4 + 1] = v.y;
        rdst[q * 4 + 2] = v.z;
        rdst[q * 4 + 3] = v.w;
      }
    } else if (u >= 0) {
      {
        int oc_l = u >> 4, grp = u & 15;
        *(float4*)&wl[oc_l * 64 + grp * 4] = *(const float4*)(
            w + (((size_t)(ocg * 8 + oc_l) * 64 + ic) * 64) + grp * 4);
      }
      if (u < 52) {
        int f2 = u + 76;
        int oc_l = f2 >> 4, grp = f2 & 15;
        *(float4*)&wl[oc_l * 64 + grp * 4] = *(const float4*)(
            w + (((size_t)(ocg * 8 + oc_l) * 64 + ic) * 64) + grp * 4);
      }
    }
    __syncthreads();
    const float* pb = patch + (od_l * 2) * 360 + (oh * 2) * 20 + ow * 2;
#pragma unroll
    for (int kd = 0; kd < 4; ++kd) {
#pragma unroll
      for (int kh = 0; kh < 4; ++kh) {
        const float* prow = pb + kd * 360 + kh * 20;
        float p0 = prow[0], p1 = prow[1], p2 = prow[2], p3 = prow[3];
        int tb = kd * 16 + kh * 4;
#pragma unroll
        for (int o = 0; o < 8; ++o) {
          float4 w4 = *(const float4*)&wl[o * 64 + tb];
          acc[o] =
              fmaf(p0, w4.x, fmaf(p1, w4.y, fmaf(p2, w4.z, fmaf(p3, w4.w, acc[o]))));
        }
      }
    }
    __syncthreads();
  }
  const int od = odg * 4 + od_l;
#pragma unroll
  for (int o = 0; o < 8; ++o) {
    int oc = ocg * 8 + o;
    out[(((size_t)(b * 128 + oc) * 8 + od) * 8 + oh) * 8 + ow] =
        fmaxf(acc[o] + bias[oc], 0.f);
  }
}

// ---------------- conv4 (unchanged) ----------------
__global__ __launch_bounds__(64) void conv_v2(const float* __restrict__ in,
                                              const float* __restrict__ w,
                                              const float* __restrict__ bias,
                                              float* __restrict__ out) {
  constexpr int IC = 128, OD = 4, ID = 8, ID2 = 64;
  __shared__ float wl[IC * 64];
  int oc = blockIdx.x % 256;
  int b = blockIdx.x / 256;
  for (int i = threadIdx.x; i < IC * 64; i += 64) wl[i] = w[oc * IC * 64 + i];
  __syncthreads();
  int s = threadIdx.x;
  int od = s >> 4, oh = (s >> 2) & 3, ow = s & 3;
  float acc = 0.f;
  for (int ic = 0; ic < IC; ++ic) {
    const float* ipb = in + (size_t)(b * IC + ic) * (ID * ID2);
    const float* wp = wl + ic * 64;
#pragma unroll
    for (int kd = 0; kd < 4; ++kd) {
      int id = od * 2 - 1 + kd;
      if ((unsigned)id < (unsigned)ID) {
#pragma unroll
        for (int kh = 0; kh < 4; ++kh) {
          int ih = oh * 2 - 1 + kh;
          if ((unsigned)ih < (unsigned)ID) {
            const float* rowp = ipb + id * ID2 + ih * ID;
#pragma unroll
            for (int kw = 0; kw < 4; ++kw) {
              int iw = ow * 2 - 1 + kw;
              if ((unsigned)iw < (unsigned)ID)
                acc = fmaf(rowp[iw], wp[kd * 16 + kh * 4 + kw], acc);
            }
          }
        }
      }
    }
  }
  acc += bias[oc];
  out[((size_t)(b * 256 + oc) * OD + od) * 16 + oh * 4 + ow] = fmaxf(acc, 0.f);
}

// ---------------- conv5 (round-12, proven) ----------------
__global__ __launch_bounds__(256) void conv_v3v(const float* __restrict__ in,
                                                const float* __restrict__ w,
                                                const float* __restrict__ bias,
                                                float* __restrict__ codes) {
  __shared__ float inl[16384];
  __shared__ float part[256];
  const int ocg = blockIdx.x & 31;
  const int b = blockIdx.x >> 5;
  const int t = threadIdx.x;
  for (int i = t; i < 4096; i += 256)
    *(float4*)&inl[i * 4] = *(const float4*)(in + (size_t)b * 16384 + i * 4);
  __syncthreads();
  const int ks = t >> 6, s = (t >> 3) & 7, oc_l = t & 7;
  const int oc = ocg * 8 + oc_l;
  const int od = s >> 2, oh = (s >> 1) & 1, ow = s & 1;
  float acc = 0.f;
  const float* wb0 = w + ((size_t)oc * 256 + ks * 64) * 64;
  const float* ib0 = inl + ks * 64 * 64;
  for (int ic = 0; ic < 64; ++ic) {
    const float* ib = ib0 + ic * 64;
    const float* wb = wb0 + ic * 64;
#pragma unroll
    for (int kd = 0; kd < 4; ++kd) {
      int id = od * 2 - 1 + kd;
      if ((unsigned)id < 4u) {
#pragma unroll
        for (int kh = 0; kh < 4; ++kh) {
          int ih = oh * 2 - 1 + kh;
          if ((unsigned)ih < 4u) {
#pragma unroll
            for (int kw = 0; kw < 4; ++kw) {
              int iw = ow * 2 - 1 + kw;
              if ((unsigned)iw < 4u)
                acc = fmaf(ib[id * 16 + ih * 4 + iw], wb[kd * 16 + kh * 4 + kw], acc);
            }
          }
        }
      }
    }
  }
  part[t] = acc;
  __syncthreads();
  if (t < 64) {
    float sv = part[t] + part[t + 64] + part[t + 128] + part[t + 192];
    int s2 = t >> 3, oc2 = ocg * 8 + (t & 7);
    codes[(b * 8 + s2) * 256 + oc2] = fmaxf(sv + bias[oc2], 0.f);
  }
}

// ---------------- coherent access helpers (relaxed, agent scope) ----------------
__device__ __forceinline__ float cload(const float* p) {
  return __hip_atomic_load(p, __ATOMIC_RELAXED, __HIP_MEMORY_SCOPE_AGENT);
}
__device__ __forceinline__ void cstore(float* p, float v) {
  __hip_atomic_store(p, v, __ATOMIC_RELAXED, __HIP_MEMORY_SCOPE_AGENT);
}

// ---------------- fence-free 8-WG barrier ----------------
__device__ __forceinline__ void gbar(int* bar, int e) {
  __syncthreads();
  if (threadIdx.x == 0) {
    int prev =
        __hip_atomic_fetch_add(&bar[0], 1, __ATOMIC_RELAXED, __HIP_MEMORY_SCOPE_AGENT);
    if (prev == 8 * e - 1) {
      __hip_atomic_store(&bar[32], e, __ATOMIC_RELAXED, __HIP_MEMORY_SCOPE_AGENT);
    } else {
      while (__hip_atomic_load(&bar[32], __ATOMIC_RELAXED, __HIP_MEMORY_SCOPE_AGENT) < e)
        __builtin_amdgcn_s_sleep(1);
    }
  }
  __syncthreads();
}

// ---------------- LayerNorm: one wave per row (stride-264 tiles) ----------------
__device__ __forceinline__ void ln_rows(const float (*sxx)[264], float (*shh)[264],
                                        const float* __restrict__ gsc,
                                        const float* __restrict__ gbi, int NJ) {
  int wv = threadIdx.x >> 6, lane = threadIdx.x & 63;
  if (wv < NJ) {
    float4 xv = *(const float4*)&sxx[wv][lane * 4];
    float s = xv.x + xv.y + xv.z + xv.w;
#pragma unroll
    for (int off = 32; off >= 1; off >>= 1) s += __shfl_xor(s, off);
    float mean = s * (1.f / 256.f);
    float d0 = xv.x - mean, d1 = xv.y - mean, d2 = xv.z - mean, d3 = xv.w - mean;
    float v = d0 * d0 + d1 * d1 + d2 * d2 + d3 * d3;
#pragma unroll
    for (int off = 32; off >= 1; off >>= 1) v += __shfl_xor(v, off);
    float rsd = 1.f / sqrtf(v * (1.f / 256.f) + 1e-5f);
    float4 s4 = *(const float4*)&gsc[lane * 4];
    float4 b4 = *(const float4*)&gbi[lane * 4];
    float4 hv;
    hv.x = d0 * rsd * s4.x + b4.x;
    hv.y = d1 * rsd * s4.y + b4.y;
    hv.z = d2 * rsd * s4.z + b4.z;
    hv.w = d3 * rsd * s4.w + b4.w;
    *(float4*)&shh[wv][lane * 4] = hv;
  }
}

// ---------------- per-chunk transformer layers (head-sliced) ----------------
// WG w owns: q/K/V head-slice cols w*32 (K/V PRIVATE to this WG); Wo k-rows
// w*32; FF1 cols w*128 (kept in LDS); FF2 k-rows w*128. Partial exchange via
// gpA/gpB (cstore/cload) + redundant reduce. 2 barriers/layer.
template <int PRE, int NJ>
__device__ void run_chunk(int b, int w, int ti, int rbase,
                          const float* __restrict__ codes,
                          const float* __restrict__ tok_emb,
                          const float* __restrict__ pos_emb,
                          const float* __restrict__ Wqkv, const float* __restrict__ Wo,
                          const float* __restrict__ ln1s, const float* __restrict__ ln1b,
                          const float* __restrict__ ln2s, const float* __restrict__ ln2b,
                          const float* __restrict__ Wff1, const float* __restrict__ bff1,
                          const float* __restrict__ Wff2, const float* __restrict__ bff2,
                          float* __restrict__ Kc, float* __restrict__ Vc,
                          float* __restrict__ gpA, float* __restrict__ gpB,
                          float (*sx)[264], float (*sh)[264], float (*f1b)[136],
                          float (*sql)[32], float (*scb)[40], float (*pvb)[32],
                          const int (*sSeq)[32], const int (*sPtr)[40], int* bar,
                          int& eb) {
  const int t = threadIdx.x;
  // ---- embedding (redundant) ----
  for (int i = t; i < NJ * 256; i += 512) {
    int j = i >> 8, c = i & 255;
    int row = PRE ? (rbase + j) : (8 + ti);
    float v;
    if (PRE)
      v = (row < 8) ? codes[(b * 8 + row) * 256 + c] : tok_emb[256 + c];  // START=1
    else
      v = tok_emb[sSeq[j][ti] * 256 + c];
    sx[j][c] = v + pos_emb[row * 256 + c];
  }
  __syncthreads();

  for (int l = 0; l < 4; ++l) {
    // ---- LN1 (redundant) ----
    ln_rows(sx, sh, ln1s + l * 256, ln1b + l * 256, NJ);
    __syncthreads();
    // ---- QKV head-slice: jobs = qkv(3) x c(32) x j(NJ) ----
    if (t < 96 * NJ) {
      int j = t / 96, r = t % 96;
      int qkv = r >> 5, c = r & 31;
      int col = qkv * 256 + w * 32 + c;
      const float* wp = Wqkv + (size_t)l * 196608 + col;
      float acc = 0.f;
#pragma unroll 8
      for (int k = 0; k < 256; ++k) acc = fmaf(sh[j][k], wp[(size_t)k * 768], acc);
      int row = PRE ? (rbase + j) : (8 + ti);
      int slot = PRE ? (b * 5) : (b * 5 + j);
      if (qkv == 0)
        sql[j][c] = acc;
      else if (qkv == 1)
        Kc[((size_t)(l * 40 + slot) * 40 + row) * 256 + w * 32 + c] = acc;  // private
      else
        Vc[((size_t)(l * 40 + slot) * 40 + row) * 256 + w * 32 + c] = acc;  // private
    }
    __syncthreads();
    // ---- scores (head w, local) ----
    if (t < NJ * 40) {
      int j = t / 40, jj = t - j * 40;
      int rowj = PRE ? (rbase + j) : (8 + ti);
      if (jj <= rowj) {
        const float* kp = Kc + ((size_t)(l * 40 + sPtr[j][jj]) * 40 + jj) * 256 + w * 32;
        float s = 0.f;
#pragma unroll
        for (int d = 0; d < 32; d += 4) {
          float4 k4 = *(const float4*)(kp + d);
          s = fmaf(sql[j][d], k4.x,
                   fmaf(sql[j][d + 1], k4.y,
                        fmaf(sql[j][d + 2], k4.z, fmaf(sql[j][d + 3], k4.w, s))));
        }
        scb[j][jj] = s * 0.17677669529663687f;  // 1/sqrt(32)
      }
    }
    __syncthreads();
    // ---- softmax (local) ----
    if (t < NJ) {
      int rowj = PRE ? (rbase + t) : (8 + ti);
      float m = -3.4e38f;
      for (int jj = 0; jj <= rowj; ++jj) m = fmaxf(m, scb[t][jj]);
      float su = 0.f;
      for (int jj = 0; jj <= rowj; ++jj) su += expf(scb[t][jj] - m);
      for (int jj = 0; jj <= rowj; ++jj) scb[t][jj] = expf(scb[t][jj] - m) / su;
    }
    __syncthreads();
    // ---- PV (local) ----
    if (t < NJ * 32) {
      int j = t >> 5, d = t & 31;
      int rowj = PRE ? (rbase + j) : (8 + ti);
      float o = 0.f;
      for (int jj = 0; jj <= rowj; ++jj)
        o = fmaf(scb[j][jj],
                 Vc[((size_t)(l * 40 + sPtr[j][jj]) * 40 + jj) * 256 + w * 32 + d], o);
      pvb[j][d] = o;
    }
    __syncthreads();
    // ---- Wo k-slice partial (k = w*32..w*32+31), all 256 cols ----
    for (int job = t; job < NJ * 256; job += 512) {
      int j = job >> 8, c = job & 255;
      const float* wp = Wo + (size_t)l * 65536 + (size_t)(w * 32) * 256 + c;
      float acc = 0.f;
#pragma unroll 8
      for (int kk = 0; kk < 32; ++kk) acc = fmaf(pvb[j][kk], wp[(size_t)kk * 256], acc);
      cstore(&gpA[(w * 5 + j) * 256 + c], acc);
    }
    gbar(bar, ++eb);
    // ---- reduce Wo partials (redundant, fixed order) + residual ----
    for (int job = t; job < NJ * 256; job += 512) {
      int j = job >> 8, c = job & 255;
      float s = 0.f;
#pragma unroll
      for (int ww = 0; ww < 8; ++ww) s += cload(&gpA[(ww * 5 + j) * 256 + c]);
      sx[j][c] += s;
    }
    __syncthreads();
    // ---- LN2 (redundant) ----
    ln_rows(sx, sh, ln2s + l * 256, ln2b + l * 256, NJ);
    __syncthreads();
    // ---- FF1 slice cols w*128 -> LDS (local) ----
    for (int job = t; job < 128 * NJ; job += 512) {
      int cl = job & 127, j = job >> 7;
      int col = w * 128 + cl;
      const float* wp = Wff1 + (size_t)l * 262144 + col;
      float acc = 0.f;
#pragma unroll 8
      for (int k = 0; k < 256; ++k) acc = fmaf(sh[j][k], wp[(size_t)k * 1024], acc);
      f1b[j][cl] = fmaxf(acc + bff1[l * 1024 + col], 0.f);
    }
    __syncthreads();
    // ---- FF2 k-slice partial (k = w*128..+127), all 256 cols ----
    for (int job = t; job < NJ * 256; job += 512) {
      int j = job >> 8, c = job & 255;
      const float* wp = Wff2 + (size_t)l * 262144 + (size_t)(w * 128) * 256 + c;
      float acc = 0.f;
#pragma unroll 8
      for (int kk = 0; kk < 128; ++kk) acc = fmaf(f1b[j][kk], wp[(size_t)kk * 256], acc);
      cstore(&gpB[(w * 5 + j) * 256 + c], acc);
    }
    gbar(bar, ++eb);
    // ---- reduce FF2 partials (redundant) + residual + bias ----
    for (int job = t; job < NJ * 256; job += 512) {
      int j = job >> 8, c = job & 255;
      float s = 0.f;
#pragma unroll
      for (int ww = 0; ww < 8; ++ww) s += cload(&gpB[(ww * 5 + j) * 256 + c]);
      sx[j][c] = sx[j][c] + s + bff2[l * 256 + c];
    }
    __syncthreads();
  }
}

// ---------------- persistent decode kernel ----------------
__global__ __launch_bounds__(512, 1) void k_dec(
    const float* __restrict__ codes, const float* __restrict__ tok_emb,
    const float* __restrict__ pos_emb, const float* __restrict__ Wqkv,
    const float* __restrict__ Wo, const float* __restrict__ ln1s,
    const float* __restrict__ ln1b, const float* __restrict__ ln2s,
    const float* __restrict__ ln2b, const float* __restrict__ Wff1,
    const float* __restrict__ bff1, const float* __restrict__ Wff2,
    const float* __restrict__ bff2, const float* __restrict__ hW1,
    const float* __restrict__ hb1, const float* __restrict__ hW2,
    const float* __restrict__ hb2, float* __restrict__ Kc, float* __restrict__ Vc,
    float* __restrict__ gpAall, float* __restrict__ gpBall, int* __restrict__ bars,
    float* __restrict__ out) {
  const int t = threadIdx.x;
  const int b = blockIdx.x >> 3;
  const int w = blockIdx.x & 7;
  int* bar = bars + b * 64;
  float* gpA = gpAall + b * 10240;
  float* gpB = gpBall + b * 10240;
  int eb = 0;

  __shared__ __align__(16) float sx[5][264];
  __shared__ __align__(16) float sh[5][264];
  __shared__ __align__(16) float f1b[5][136];
  __shared__ __align__(16) float sql[5][32];
  __shared__ float scb[5][40];
  __shared__ __align__(16) float pvb[5][32];
  __shared__ __align__(16) float sLg[5][64];
  __shared__ int sSeq[5][32], sPtr[5][40];
  __shared__ float sLls[5];
  __shared__ float bmF[360];
  __shared__ int bmI[400];

  for (int i = t; i < 160; i += 512) sSeq[i >> 5][i & 31] = ((i & 31) == 0) ? 1 : 0;
  for (int i = t; i < 200; i += 512) sPtr[i / 40][i % 40] = b * 5;
  if (t < 5) sLls[t] = (t == 0) ? 0.f : -100000.0f;
  __syncthreads();

  for (int ti = 0; ti < 31; ++ti) {
    const bool pre = (ti == 0);
    if (pre) {
      run_chunk<1, 5>(b, w, ti, 0, codes, tok_emb, pos_emb, Wqkv, Wo, ln1s, ln1b, ln2s,
                      ln2b, Wff1, bff1, Wff2, bff2, Kc, Vc, gpA, gpB, sx, sh, f1b, sql,
                      scb, pvb, sSeq, sPtr, bar, eb);
      run_chunk<1, 4>(b, w, ti, 5, codes, tok_emb, pos_emb, Wqkv, Wo, ln1s, ln1b, ln2s,
                      ln2b, Wff1, bff1, Wff2, bff2, Kc, Vc, gpA, gpB, sx, sh, f1b, sql,
                      scb, pvb, sSeq, sPtr, bar, eb);
    } else {
      run_chunk<0, 5>(b, w, ti, 0, codes, tok_emb, pos_emb, Wqkv, Wo, ln1s, ln1b, ln2s,
                      ln2b, Wff1, bff1, Wff2, bff2, Kc, Vc, gpA, gpB, sx, sh, f1b, sql,
                      scb, pvb, sSeq, sPtr, bar, eb);
    }
    // ---- head (redundant per WG; weights L2-shared across groups per XCD) ----
    {
      const int NJH = pre ? 1 : 5;
      for (int job = t; job < 256 * NJH; job += 512) {
        int c = job & 255, j = job >> 8;
        int src = pre ? 3 : j;  // prefill chunk2: row 8 = local j 3
        const float* wp = hW1 + c;
        float acc = 0.f;
#pragma unroll 8
        for (int k = 0; k < 256; ++k) acc = fmaf(sx[src][k], wp[(size_t)k * 256], acc);
        sh[j][c] = fmaxf(acc + hb1[c], 0.f);
      }
      __syncthreads();
      for (int job = t; job < 64 * NJH; job += 512) {
        int c = job & 63, j = job >> 6;
        const float* wp = hW2 + c;
        float acc = 0.f;
#pragma unroll 8
        for (int k = 0; k < 256; ++k) acc = fmaf(sh[j][k], wp[(size_t)k * 64], acc);
        sLg[j][c] = acc + hb2[c];
      }
      __syncthreads();
      if (pre) {
        for (int i = t; i < 320; i += 512) {
          int j = i >> 6, c = i & 63;
          if (j > 0) sLg[j][c] = sLg[0][c];
        }
        __syncthreads();
      }
    }
    // ---- beam update (replicated, exact tie semantics) ----
    {
      float* bdist = bmF;
      float* bd = bmF + 320;
      float* nll = bmF + 345;
      float* rm = bmF + 350;
      float* rs = bmF + 355;
      int* osq = bmI;
      int* opt = bmI + 160;
      int* bc = bmI + 360;
      int* nts = bmI + 385;
      int* oldx = bmI + 390;
      for (int i = t; i < 160; i += 512) osq[i] = sSeq[i >> 5][i & 31];
      for (int i = t; i < 200; i += 512) opt[i] = sPtr[i / 40][i % 40];
      __syncthreads();
      if (t < 5) {
        float m = -3.4e38f;
        for (int j = 0; j < 64; ++j) m = fmaxf(m, sLg[t][j]);
        float s = 0.f;
        for (int j = 0; j < 64; ++j) s += expf(sLg[t][j] - m);
        rm[t] = m;
        rs[t] = s;
      }
      __syncthreads();
      for (int i = t; i < 320; i += 512) {
        int r = i >> 6;
        bdist[i] = logf(expf(sLg[r][i & 63] - rm[r]) / rs[r] + 1e-8f);
      }
      __syncthreads();
      if (t < 5) {
        float pv = 3.4e38f;
        int pi = -1;
        for (int r = 0; r < 5; ++r) {
          float bv = -3.4e38f;
          int bi = -1;
          for (int j = 0; j < 64; ++j) {
            float v = bdist[t * 64 + j];
            bool lessprev = (v < pv) || (v == pv && j > pi);
            if (lessprev && v > bv) { bv = v; bi = j; }
          }
          bd[t * 5 + r] = bv;
          bc[t * 5 + r] = bi;
          pv = bv;
          pi = bi;
        }
      }
      __syncthreads();
      if (t == 0) {
        float pv = 3.4e38f;
        int pi = -1;
        for (int r = 0; r < 5; ++r) {
          float bv = -3.4e38f;
          int bi = -1;
          for (int idx = 0; idx < 25; ++idx) {
            int kb = idx / 5, jj = idx % 5;
            float v = bd[kb * 5 + jj] + sLls[kb];
            bool lessprev = (v < pv) || (v == pv && idx > pi);
            if (lessprev && v > bv) { bv = v; bi = idx; }
          }
          int kb = bi / 5, jj = bi % 5;
          int tok = bc[kb * 5 + jj];
          nts[r] = tok;
          oldx[r] = kb;
          nll[r] = (tok == 2) ? (bv - 100000.0f) : bv;
          pv = bv;
          pi = bi;
        }
      }
      __syncthreads();
      for (int i = t; i < 160; i += 512) {
        int bm = i >> 5, j2 = i & 31;
        int v = osq[oldx[bm] * 32 + j2];
        if (j2 == ti + 1) v = nts[bm];
        sSeq[bm][j2] = v;
      }
      int r1 = 8 + ti;
      for (int i = t; i < 200; i += 512) {
        int bm = i / 40, j2 = i % 40;
        sPtr[bm][j2] = (j2 <= r1) ? opt[oldx[bm] * 40 + j2] : (b * 5 + bm);
      }
      if (t < 5) sLls[t] = nll[t];
      __syncthreads();
    }
  }
  if (w == 0) {
    for (int i = t; i < 160; i += 512) out[b * 160 + i] = (float)sSeq[i >> 5][i & 31];
    if (t < 5) out[1280 + b * 5 + t] = sLls[t];
  }
}

// ---------------- host ----------------
extern "C" void kernel_launch(void* const* d_in, const int* in_sizes, int n_in,
                              void* d_out, int out_size, void* d_ws, size_t ws_size,
                              hipStream_t stream) {
  const float* voxels = (const float*)d_in[0];
  const float* ck1 = (const float*)d_in[1];
  const float* cb1 = (const float*)d_in[2];
  const float* ck2 = (const float*)d_in[3];
  const float* cb2 = (const float*)d_in[4];
  const float* ck3 = (const float*)d_in[5];
  const float* cb3 = (const float*)d_in[6];
  const float* ck4 = (const float*)d_in[7];
  const float* cb4 = (const float*)d_in[8];
  const float* ck5 = (const float*)d_in[9];
  const float* cb5 = (const float*)d_in[10];
  const float* tok_emb = (const float*)d_in[11];
  const float* pos_emb = (const float*)d_in[12];
  const float* Wqkv = (const float*)d_in[13];
  const float* Wo = (const float*)d_in[14];
  const float* ln1s = (const float*)d_in[15];
  const float* ln1b = (const float*)d_in[16];
  const float* ln2s = (const float*)d_in[17];
  const float* ln2b = (const float*)d_in[18];
  const float* Wff1 = (const float*)d_in[19];
  const float* bff1 = (const float*)d_in[20];
  const float* Wff2 = (const float*)d_in[21];
  const float* bff2 = (const float*)d_in[22];
  const float* hW1 = (const float*)d_in[23];
  const float* hb1 = (const float*)d_in[24];
  const float* hW2 = (const float*)d_in[25];
  const float* hb2 = (const float*)d_in[26];

  float* ws = (float*)d_ws;
  float* c1 = ws;              // 8,388,608 f
  float* c2 = c1 + 8388608;    // 2,097,152 f
  float* c3 = c2 + 2097152;    //   524,288 f
  float* c4 = c3 + 524288;     //   131,072 f
  float* codes = c4 + 131072;  //    16,384 f
  float* Kc = ws;              // 1,638,400 f (aliases c1, dead after conv_t2v)
  float* Vc = Kc + 1638400;    // 1,638,400 f
  float* gpA = codes + 16384;  // 81,920 f  [8 groups][8 w][5][256]
  float* gpB = gpA + 81920;    // 81,920 f
  int* bars = (int*)(gpB + 81920);  // 512 i

  conv_v1<1, 32, 32, 128><<<8 * 32 * 128, 256, 0, stream>>>(voxels, ck1, cb1, c1);
  conv_t2v<<<1024, 256, 0, stream>>>(c1, ck2, cb2, c2);
  conv_t3v<<<256, 256, 0, stream>>>(c2, ck3, cb3, c3);
  conv_v2<<<8 * 256, 64, 0, stream>>>(c3, ck4, cb4, c4);
  conv_v3v<<<256, 256, 0, stream>>>(c4, ck5, cb5, codes);

  hipMemsetAsync(bars, 0, 512 * sizeof(int), stream);
  k_dec<<<64, 512, 0, stream>>>(codes, tok_emb, pos_emb, Wqkv, Wo, ln1s, ln1b, ln2s,
                                ln2b, Wff1, bff1, Wff2, bff2, hW1, hb1, hW2, hb2, Kc,
                                Vc, gpA, gpB, bars, (float*)d_out);
}